// Round 1
// baseline (2780.221 us; speedup 1.0000x reference)
//
#include <hip/hip_runtime.h>

// Transformer block, fp32 baseline (round 1: correctness first).
// B=2 T=2048 E=1024 H=16 DH=64.
// Stages: LN1 -> QKV -> flash attn (quirk permutation folded into epilogue)
//         -> fc+bias+x -> LN2 -> FF1+gelu -> FF2+bias+h.

#define En 1024
#define Hn 16
#define DHn 64
#define Bn 2
#define Tn 2048
#define Mrows 4096  // B*T

__device__ __forceinline__ float gelu_f(float x) {
    // faithful: 0.5*x*(1+tanh(sqrt(2/pi)*x + 0.044715*x^3))  (no sqrt on cubic)
    float inner = 0.79788456080286535588f * x + 0.044715f * x * x * x;
    return 0.5f * x * (1.0f + tanhf(inner));
}

// ---------------- LayerNorm: one block per row ----------------
__global__ __launch_bounds__(256) void ln_kernel(
    const float* __restrict__ in, const float* __restrict__ sc,
    const float* __restrict__ sh, float* __restrict__ out)
{
    int row = blockIdx.x;
    int tid = threadIdx.x;
    float4 v = ((const float4*)(in + (size_t)row * En))[tid];
    float s  = v.x + v.y + v.z + v.w;
    float s2 = v.x*v.x + v.y*v.y + v.z*v.z + v.w*v.w;
    #pragma unroll
    for (int off = 32; off > 0; off >>= 1) {
        s  += __shfl_down(s,  off);
        s2 += __shfl_down(s2, off);
    }
    __shared__ float red[2][4];
    int wave = tid >> 6, lane = tid & 63;
    if (lane == 0) { red[0][wave] = s; red[1][wave] = s2; }
    __syncthreads();
    s  = red[0][0] + red[0][1] + red[0][2] + red[0][3];
    s2 = red[1][0] + red[1][1] + red[1][2] + red[1][3];
    float mean = s * (1.0f / En);
    float var  = s2 * (1.0f / En) - mean * mean;
    float r = rsqrtf(var + 1e-5f);
    float4 scv = ((const float4*)sc)[tid];
    float4 shv = ((const float4*)sh)[tid];
    float4 o;
    o.x = scv.x * (v.x - mean) * r + shv.x;
    o.y = scv.y * (v.y - mean) * r + shv.y;
    o.z = scv.z * (v.z - mean) * r + shv.z;
    o.w = scv.w * (v.w - mean) * r + shv.w;
    ((float4*)(out + (size_t)row * En))[tid] = o;
}

// ---------------- Generic fp32 GEMM: 64x64 tile, BK=16, 4x4/thread ----------------
#define BM 64
#define BN 64
#define BK 16

template<int ACT, int RES>
__global__ __launch_bounds__(256) void gemm_kernel(
    const float* __restrict__ A, int lda,
    const float* __restrict__ Bm, int ldb,
    float* __restrict__ C, int ldc,
    int K,
    const float* __restrict__ bias,
    const float* __restrict__ resid)
{
    __shared__ float As[BK][BM + 4];  // transposed A tile: As[k][m], +4 pad keeps 16B align
    __shared__ float Bs[BK][BN];
    int tid = threadIdx.x;
    int m0 = blockIdx.x * BM;
    int n0 = blockIdx.y * BN;
    int tx = tid & 15, ty = tid >> 4;
    int ar = tid >> 2;          // 0..63  A-load row
    int ak = (tid & 3) * 4;     // 0,4,8,12 A-load k offset (float4)
    int kb = tid >> 4;          // 0..15  B-load k row
    int nb = (tid & 15) * 4;    // B-load col offset (float4)
    const float* Aptr = A + (size_t)(m0 + ar) * lda + ak;
    const float* Bptr = Bm + (size_t)kb * ldb + n0 + nb;
    float acc[4][4] = {};
    for (int k0 = 0; k0 < K; k0 += BK) {
        float4 av = *(const float4*)(Aptr + k0);
        float4 bv = *(const float4*)(Bptr + (size_t)k0 * ldb);
        __syncthreads();
        As[ak + 0][ar] = av.x;
        As[ak + 1][ar] = av.y;
        As[ak + 2][ar] = av.z;
        As[ak + 3][ar] = av.w;
        *(float4*)&Bs[kb][nb] = bv;
        __syncthreads();
        #pragma unroll
        for (int kk = 0; kk < BK; ++kk) {
            float4 a4 = *(const float4*)&As[kk][ty * 4];
            float4 b4 = *(const float4*)&Bs[kk][tx * 4];
            float a[4] = {a4.x, a4.y, a4.z, a4.w};
            float b[4] = {b4.x, b4.y, b4.z, b4.w};
            #pragma unroll
            for (int i = 0; i < 4; ++i)
                #pragma unroll
                for (int j = 0; j < 4; ++j)
                    acc[i][j] += a[i] * b[j];
        }
    }
    float4 b4 = *(const float4*)(bias + n0 + tx * 4);
    float bb[4] = {b4.x, b4.y, b4.z, b4.w};
    #pragma unroll
    for (int i = 0; i < 4; ++i) {
        int row = m0 + ty * 4 + i;
        float o[4];
        #pragma unroll
        for (int j = 0; j < 4; ++j) {
            float vv = acc[i][j] + bb[j];
            if (ACT) vv = gelu_f(vv);
            o[j] = vv;
        }
        if (RES) {
            float4 r4 = *(const float4*)(resid + (size_t)row * ldc + n0 + tx * 4);
            o[0] += r4.x; o[1] += r4.y; o[2] += r4.z; o[3] += r4.w;
        }
        float4 o4 = {o[0], o[1], o[2], o[3]};
        *(float4*)(C + (size_t)row * ldc + n0 + tx * 4) = o4;
    }
}

// ---------------- QKV projection: grid (M/64, H, 3) ----------------
// out layout (H, B*T, DH): offset h*Mrows*DH + row*DH + d  (== (h*B+b, t) blocks)
__global__ __launch_bounds__(256) void qkv_kernel(
    const float* __restrict__ xn,
    const float* __restrict__ Wq, const float* __restrict__ Wk, const float* __restrict__ Wv,
    float* __restrict__ qb, float* __restrict__ kbuf, float* __restrict__ vbuf)
{
    int h = blockIdx.y, sel = blockIdx.z;
    const float* W = (sel == 0) ? Wq : (sel == 1) ? Wk : Wv;
    float* out = (sel == 0) ? qb : (sel == 1) ? kbuf : vbuf;
    W   += (size_t)h * En * DHn;
    out += (size_t)h * Mrows * DHn;

    __shared__ float As[BK][BM + 4];
    __shared__ float Bs[BK][BN];
    int tid = threadIdx.x;
    int m0 = blockIdx.x * BM;
    int tx = tid & 15, ty = tid >> 4;
    int ar = tid >> 2;
    int ak = (tid & 3) * 4;
    int kb = tid >> 4;
    int nb = (tid & 15) * 4;
    const float* Aptr = xn + (size_t)(m0 + ar) * En + ak;
    const float* Bptr = W + (size_t)kb * DHn + nb;
    float acc[4][4] = {};
    for (int k0 = 0; k0 < En; k0 += BK) {
        float4 av = *(const float4*)(Aptr + k0);
        float4 bv = *(const float4*)(Bptr + (size_t)k0 * DHn);
        __syncthreads();
        As[ak + 0][ar] = av.x;
        As[ak + 1][ar] = av.y;
        As[ak + 2][ar] = av.z;
        As[ak + 3][ar] = av.w;
        *(float4*)&Bs[kb][nb] = bv;
        __syncthreads();
        #pragma unroll
        for (int kk = 0; kk < BK; ++kk) {
            float4 a4 = *(const float4*)&As[kk][ty * 4];
            float4 b4 = *(const float4*)&Bs[kk][tx * 4];
            float a[4] = {a4.x, a4.y, a4.z, a4.w};
            float b[4] = {b4.x, b4.y, b4.z, b4.w};
            #pragma unroll
            for (int i = 0; i < 4; ++i)
                #pragma unroll
                for (int j = 0; j < 4; ++j)
                    acc[i][j] += a[i] * b[j];
        }
    }
    #pragma unroll
    for (int i = 0; i < 4; ++i) {
        int row = m0 + ty * 4 + i;
        float4 o4 = {acc[i][0], acc[i][1], acc[i][2], acc[i][3]};
        *(float4*)(out + (size_t)row * DHn + tx * 4) = o4;
    }
}

// ---------------- Flash causal attention, thread = one query row ----------------
// q/k/v layout (H, B, T, DH); writes the "quirk" permutation directly:
// concat[b, d*32 + t/64, h*64 + t%64] = ctx[b,h,t,d]
__global__ __launch_bounds__(256) void attn_kernel(
    const float* __restrict__ q, const float* __restrict__ ksrc,
    const float* __restrict__ vsrc, float* __restrict__ concat)
{
    int g = blockIdx.x;           // h*B + b
    int h = g / Bn, b = g % Bn;
    const float* qg = q    + (size_t)g * Tn * DHn;
    const float* kg = ksrc + (size_t)g * Tn * DHn;
    const float* vg = vsrc + (size_t)g * Tn * DHn;
    int qbase = blockIdx.y * 256;
    int tid = threadIdx.x;
    int t = qbase + tid;

    float qreg[64];
    const float4* qrow = (const float4*)(qg + (size_t)t * DHn);
    #pragma unroll
    for (int c = 0; c < 16; ++c) {
        float4 tmp = qrow[c];
        qreg[c * 4 + 0] = tmp.x; qreg[c * 4 + 1] = tmp.y;
        qreg[c * 4 + 2] = tmp.z; qreg[c * 4 + 3] = tmp.w;
    }

    __shared__ float Ks[64][64];
    __shared__ float Vs[64][64];
    float m = -1e30f, l = 0.0f;
    float o[64] = {};
    int ntiles = (qbase >> 6) + 4;
    for (int tile = 0; tile < ntiles; ++tile) {
        int s0 = tile * 64;
        __syncthreads();
        #pragma unroll
        for (int rr = 0; rr < 4; ++rr) {
            int r = (tid >> 4) + rr * 16;
            int d4 = (tid & 15) * 4;
            *(float4*)&Ks[r][d4] = *(const float4*)(kg + (size_t)(s0 + r) * DHn + d4);
            *(float4*)&Vs[r][d4] = *(const float4*)(vg + (size_t)(s0 + r) * DHn + d4);
        }
        __syncthreads();
        int smax = t - s0 + 1;
        if (smax > 64) smax = 64;
        for (int s = 0; s < smax; ++s) {
            float d0 = 0, d1 = 0, d2 = 0, d3 = 0;
            #pragma unroll
            for (int d = 0; d < 64; d += 4) {
                d0 += qreg[d + 0] * Ks[s][d + 0];
                d1 += qreg[d + 1] * Ks[s][d + 1];
                d2 += qreg[d + 2] * Ks[s][d + 2];
                d3 += qreg[d + 3] * Ks[s][d + 3];
            }
            float logit = ((d0 + d1) + (d2 + d3)) * 0.125f;  // 1/sqrt(64)
            if (logit <= m) {
                float p = __expf(logit - m);
                l += p;
                #pragma unroll
                for (int d = 0; d < 64; ++d) o[d] += p * Vs[s][d];
            } else {
                float corr = __expf(m - logit);
                m = logit;
                l = l * corr + 1.0f;
                #pragma unroll
                for (int d = 0; d < 64; ++d) o[d] = o[d] * corr + Vs[s][d];
            }
        }
    }
    float inv = 1.0f / l;
    float* cb = concat + (size_t)b * Tn * En + (size_t)(t >> 6) * En + h * DHn + (t & 63);
    #pragma unroll
    for (int d = 0; d < 64; ++d)
        cb[(size_t)d * 32 * En] = o[d] * inv;
}

extern "C" void kernel_launch(void* const* d_in, const int* in_sizes, int n_in,
                              void* d_out, int out_size, void* d_ws, size_t ws_size,
                              hipStream_t stream) {
    const float* x     = (const float*)d_in[0];
    const float* Wq    = (const float*)d_in[1];
    const float* Wk    = (const float*)d_in[2];
    const float* Wv    = (const float*)d_in[3];
    const float* fc_w  = (const float*)d_in[4];
    const float* fc_b  = (const float*)d_in[5];
    const float* ln1_s = (const float*)d_in[6];
    const float* ln1_b = (const float*)d_in[7];
    const float* ln2_s = (const float*)d_in[8];
    const float* ln2_b = (const float*)d_in[9];
    const float* ff_w1 = (const float*)d_in[10];
    const float* ff_b1 = (const float*)d_in[11];
    const float* ff_w2 = (const float*)d_in[12];
    const float* ff_b2 = (const float*)d_in[13];
    float* out = (float*)d_out;
    (void)in_sizes; (void)n_in; (void)out_size; (void)ws_size;

    float* ws = (float*)d_ws;
    // buffer plan (floats), reuse across stream-ordered stages:
    float* xn   = ws;               // [0, 4M)    LN1 out; dead after qkv
    float* qb   = ws + 4194304;     // [4M, 8M)
    float* kbuf = ws + 8388608;     // [8M,12M)
    float* vbuf = ws + 12582912;    // [12M,16M)
    float* cat  = ws;               // reuse xn   (attn out, quirk layout)
    float* hbuf = ws + 4194304;     // reuse qb   (residual h)
    float* ynb  = ws + 8388608;     // reuse kbuf (LN2 out)
    float* y1   = ws + 12582912;    // reuse vbuf; needs 16M floats -> ws >= 112 MB

    ln_kernel<<<dim3(Mrows), dim3(256), 0, stream>>>(x, ln1_s, ln1_b, xn);
    qkv_kernel<<<dim3(Mrows / 64, Hn, 3), dim3(256), 0, stream>>>(
        xn, Wq, Wk, Wv, qb, kbuf, vbuf);
    attn_kernel<<<dim3(Hn * Bn, Tn / 256), dim3(256), 0, stream>>>(
        qb, kbuf, vbuf, cat);
    gemm_kernel<0, 1><<<dim3(Mrows / 64, En / 64), dim3(256), 0, stream>>>(
        cat, En, fc_w, En, hbuf, En, En, fc_b, x);
    ln_kernel<<<dim3(Mrows), dim3(256), 0, stream>>>(hbuf, ln2_s, ln2_b, ynb);
    gemm_kernel<1, 0><<<dim3(Mrows / 64, 4 * En / 64), dim3(256), 0, stream>>>(
        ynb, En, ff_w1, 4 * En, y1, 4 * En, En, ff_b1, nullptr);
    gemm_kernel<0, 1><<<dim3(Mrows / 64, En / 64), dim3(256), 0, stream>>>(
        y1, 4 * En, ff_w2, En, out, En, 4 * En, ff_b2, hbuf);
}

// Round 3
// 1579.531 us; speedup vs baseline: 1.7602x; 1.7602x over previous
//
#include <hip/hip_runtime.h>

// Transformer block. B=2 T=2048 E=1024 H=16 DH=64.
// R3: fix MFMA intrinsic arity (missing 0,0,0 on PV call). Otherwise identical
// to R2: bf16 MFMA flash attention; fp32 GEMMs (MFMA next round).

#define En 1024
#define Hn 16
#define DHn 64
#define Bn 2
#define Tn 2048
#define Mrows 4096  // B*T

typedef __attribute__((ext_vector_type(8))) short bf16x8;
typedef __attribute__((ext_vector_type(4))) float f32x4;

__device__ __forceinline__ short f2bf(float f) {
    unsigned u = __float_as_uint(f);
    u += 0x7FFFu + ((u >> 16) & 1u);   // round-to-nearest-even
    return (short)(u >> 16);
}

__device__ __forceinline__ float gelu_f(float x) {
    float inner = 0.79788456080286535588f * x + 0.044715f * x * x * x;
    return 0.5f * x * (1.0f + tanhf(inner));
}

// ---------------- LayerNorm: one block per row ----------------
__global__ __launch_bounds__(256) void ln_kernel(
    const float* __restrict__ in, const float* __restrict__ sc,
    const float* __restrict__ sh, float* __restrict__ out)
{
    int row = blockIdx.x;
    int tid = threadIdx.x;
    float4 v = ((const float4*)(in + (size_t)row * En))[tid];
    float s  = v.x + v.y + v.z + v.w;
    float s2 = v.x*v.x + v.y*v.y + v.z*v.z + v.w*v.w;
    #pragma unroll
    for (int off = 32; off > 0; off >>= 1) {
        s  += __shfl_down(s,  off);
        s2 += __shfl_down(s2, off);
    }
    __shared__ float red[2][4];
    int wave = tid >> 6, lane = tid & 63;
    if (lane == 0) { red[0][wave] = s; red[1][wave] = s2; }
    __syncthreads();
    s  = red[0][0] + red[0][1] + red[0][2] + red[0][3];
    s2 = red[1][0] + red[1][1] + red[1][2] + red[1][3];
    float mean = s * (1.0f / En);
    float var  = s2 * (1.0f / En) - mean * mean;
    float r = rsqrtf(var + 1e-5f);
    float4 scv = ((const float4*)sc)[tid];
    float4 shv = ((const float4*)sh)[tid];
    float4 o;
    o.x = scv.x * (v.x - mean) * r + shv.x;
    o.y = scv.y * (v.y - mean) * r + shv.y;
    o.z = scv.z * (v.z - mean) * r + shv.z;
    o.w = scv.w * (v.w - mean) * r + shv.w;
    ((float4*)(out + (size_t)row * En))[tid] = o;
}

// ---------------- Generic fp32 GEMM: 64x64 tile, BK=16, 4x4/thread ----------------
#define BM 64
#define BN 64
#define BK 16

template<int ACT, int RES>
__global__ __launch_bounds__(256) void gemm_kernel(
    const float* __restrict__ A, int lda,
    const float* __restrict__ Bm, int ldb,
    float* __restrict__ C, int ldc,
    int K,
    const float* __restrict__ bias,
    const float* __restrict__ resid)
{
    __shared__ float As[BK][BM + 4];
    __shared__ float Bs[BK][BN];
    int tid = threadIdx.x;
    int m0 = blockIdx.x * BM;
    int n0 = blockIdx.y * BN;
    int tx = tid & 15, ty = tid >> 4;
    int ar = tid >> 2;
    int ak = (tid & 3) * 4;
    int kb = tid >> 4;
    int nb = (tid & 15) * 4;
    const float* Aptr = A + (size_t)(m0 + ar) * lda + ak;
    const float* Bptr = Bm + (size_t)kb * ldb + n0 + nb;
    float acc[4][4] = {};
    for (int k0 = 0; k0 < K; k0 += BK) {
        float4 av = *(const float4*)(Aptr + k0);
        float4 bv = *(const float4*)(Bptr + (size_t)k0 * ldb);
        __syncthreads();
        As[ak + 0][ar] = av.x;
        As[ak + 1][ar] = av.y;
        As[ak + 2][ar] = av.z;
        As[ak + 3][ar] = av.w;
        *(float4*)&Bs[kb][nb] = bv;
        __syncthreads();
        #pragma unroll
        for (int kk = 0; kk < BK; ++kk) {
            float4 a4 = *(const float4*)&As[kk][ty * 4];
            float4 b4 = *(const float4*)&Bs[kk][tx * 4];
            float a[4] = {a4.x, a4.y, a4.z, a4.w};
            float b[4] = {b4.x, b4.y, b4.z, b4.w};
            #pragma unroll
            for (int i = 0; i < 4; ++i)
                #pragma unroll
                for (int j = 0; j < 4; ++j)
                    acc[i][j] += a[i] * b[j];
        }
    }
    float4 b4 = *(const float4*)(bias + n0 + tx * 4);
    float bb[4] = {b4.x, b4.y, b4.z, b4.w};
    #pragma unroll
    for (int i = 0; i < 4; ++i) {
        int row = m0 + ty * 4 + i;
        float o[4];
        #pragma unroll
        for (int j = 0; j < 4; ++j) {
            float vv = acc[i][j] + bb[j];
            if (ACT) vv = gelu_f(vv);
            o[j] = vv;
        }
        if (RES) {
            float4 r4 = *(const float4*)(resid + (size_t)row * ldc + n0 + tx * 4);
            o[0] += r4.x; o[1] += r4.y; o[2] += r4.z; o[3] += r4.w;
        }
        float4 o4 = {o[0], o[1], o[2], o[3]};
        *(float4*)(C + (size_t)row * ldc + n0 + tx * 4) = o4;
    }
}

// ---------------- QKV projection: grid (M/64, H, 3) ----------------
__global__ __launch_bounds__(256) void qkv_kernel(
    const float* __restrict__ xn,
    const float* __restrict__ Wq, const float* __restrict__ Wk, const float* __restrict__ Wv,
    float* __restrict__ qb, float* __restrict__ kbuf, float* __restrict__ vbuf)
{
    int h = blockIdx.y, sel = blockIdx.z;
    const float* W = (sel == 0) ? Wq : (sel == 1) ? Wk : Wv;
    float* out = (sel == 0) ? qb : (sel == 1) ? kbuf : vbuf;
    W   += (size_t)h * En * DHn;
    out += (size_t)h * Mrows * DHn;

    __shared__ float As[BK][BM + 4];
    __shared__ float Bs[BK][BN];
    int tid = threadIdx.x;
    int m0 = blockIdx.x * BM;
    int tx = tid & 15, ty = tid >> 4;
    int ar = tid >> 2;
    int ak = (tid & 3) * 4;
    int kb = tid >> 4;
    int nb = (tid & 15) * 4;
    const float* Aptr = xn + (size_t)(m0 + ar) * En + ak;
    const float* Bptr = W + (size_t)kb * DHn + nb;
    float acc[4][4] = {};
    for (int k0 = 0; k0 < En; k0 += BK) {
        float4 av = *(const float4*)(Aptr + k0);
        float4 bv = *(const float4*)(Bptr + (size_t)k0 * DHn);
        __syncthreads();
        As[ak + 0][ar] = av.x;
        As[ak + 1][ar] = av.y;
        As[ak + 2][ar] = av.z;
        As[ak + 3][ar] = av.w;
        *(float4*)&Bs[kb][nb] = bv;
        __syncthreads();
        #pragma unroll
        for (int kk = 0; kk < BK; ++kk) {
            float4 a4 = *(const float4*)&As[kk][ty * 4];
            float4 b4 = *(const float4*)&Bs[kk][tx * 4];
            float a[4] = {a4.x, a4.y, a4.z, a4.w};
            float b[4] = {b4.x, b4.y, b4.z, b4.w};
            #pragma unroll
            for (int i = 0; i < 4; ++i)
                #pragma unroll
                for (int j = 0; j < 4; ++j)
                    acc[i][j] += a[i] * b[j];
        }
    }
    #pragma unroll
    for (int i = 0; i < 4; ++i) {
        int row = m0 + ty * 4 + i;
        float4 o4 = {acc[i][0], acc[i][1], acc[i][2], acc[i][3]};
        *(float4*)(out + (size_t)row * DHn + tx * 4) = o4;
    }
}

// ---------------- MFMA flash attention ----------------
// Block = (g, 64-query tile). 4 waves; wave owns 16 query rows.
// K staged row-major bf16, V staged transposed (d-major) bf16, both XOR-swizzled
// (chunk ^= row&7, 128B pitch) so all fragment ds_read_b128 hit the bank floor.
// Quirk epilogue: cat[b, d*32 + t/64, h*64 + t%64] = ctx[b,h,t,d].
__global__ __launch_bounds__(256) void attn_mfma(
    const float* __restrict__ q, const float* __restrict__ ksrc,
    const float* __restrict__ vsrc, float* __restrict__ cat)
{
    int g = blockIdx.x, qt = blockIdx.y;
    int h = g >> 1, b = g & 1;
    const float* qg = q    + (size_t)g * Tn * DHn;
    const float* kg = ksrc + (size_t)g * Tn * DHn;
    const float* vg = vsrc + (size_t)g * Tn * DHn;
    int q0 = qt * 64;
    int tid = threadIdx.x, wave = tid >> 6, lane = tid & 63;
    int m = lane & 15, gq = lane >> 4;

    __shared__ short Ks[4096];      // [key(64)][d(64)] swizzled
    __shared__ short Vt[4096];      // [d(64)][key(64)] swizzled
    __shared__ short Ps[4][1024];   // per-wave [q(16)][key(64)] swizzled

    // Q A-fragments: A[m][k] with m=lane&15, k=gq*8+j (per 32-wide d block)
    bf16x8 qf[2];
    {
        const float* qp = qg + (size_t)(q0 + wave * 16 + m) * DHn + gq * 8;
        #pragma unroll
        for (int db = 0; db < 2; ++db) {
            float4 a  = *(const float4*)(qp + db * 32);
            float4 bq = *(const float4*)(qp + db * 32 + 4);
            bf16x8 f;
            f[0]=f2bf(a.x);  f[1]=f2bf(a.y);  f[2]=f2bf(a.z);  f[3]=f2bf(a.w);
            f[4]=f2bf(bq.x); f[5]=f2bf(bq.y); f[6]=f2bf(bq.z); f[7]=f2bf(bq.w);
            qf[db] = f;
        }
    }

    f32x4 o[4];
    #pragma unroll
    for (int i = 0; i < 4; ++i) o[i] = (f32x4){0.f, 0.f, 0.f, 0.f};
    float mrun[4] = {-1e30f, -1e30f, -1e30f, -1e30f};
    float lrun[4] = {0.f, 0.f, 0.f, 0.f};

    int R  = tid >> 2;     // staging row 0..63
    int c2 = tid & 3;      // staging 16-elem column block

    for (int kt = 0; kt <= qt; ++kt) {
        int k0 = kt * 64;
        __syncthreads();
        {   // stage K (row-major) and V (transposed) as swizzled bf16
            const float* ksp = kg + (size_t)(k0 + R) * DHn + c2 * 16;
            const float* vsp = vg + (size_t)(k0 + R) * DHn + c2 * 16;
            float tk[16], tv[16];
            #pragma unroll
            for (int c = 0; c < 4; ++c) {
                float4 kv = *(const float4*)(ksp + c * 4);
                float4 vv = *(const float4*)(vsp + c * 4);
                tk[c*4+0]=kv.x; tk[c*4+1]=kv.y; tk[c*4+2]=kv.z; tk[c*4+3]=kv.w;
                tv[c*4+0]=vv.x; tv[c*4+1]=vv.y; tv[c*4+2]=vv.z; tv[c*4+3]=vv.w;
            }
            bf16x8 f0, f1;
            #pragma unroll
            for (int e = 0; e < 8; ++e) { f0[e] = f2bf(tk[e]); f1[e] = f2bf(tk[8 + e]); }
            *(bf16x8*)&Ks[R * 64 + (((c2 * 2    ) ^ (R & 7)) << 3)] = f0;
            *(bf16x8*)&Ks[R * 64 + (((c2 * 2 + 1) ^ (R & 7)) << 3)] = f1;
            #pragma unroll
            for (int i = 0; i < 16; ++i) {
                int d = c2 * 16 + i;
                Vt[d * 64 + ((((R >> 3) ^ (d & 7)) << 3) | (R & 7))] = f2bf(tv[i]);
            }
        }
        __syncthreads();

        bool diag = (kt == qt);
        float s4[4][4];
        #pragma unroll
        for (int ct = 0; ct < 4; ++ct) {
            if (diag && ct > wave) {   // fully masked sub-tile: skip MFMA
                s4[ct][0] = s4[ct][1] = s4[ct][2] = s4[ct][3] = -1e30f;
                continue;
            }
            f32x4 acc = (f32x4){0.f, 0.f, 0.f, 0.f};
            int row = ct * 16 + m;     // key within tile
            #pragma unroll
            for (int db = 0; db < 2; ++db) {
                bf16x8 kf = *(const bf16x8*)&Ks[row * 64 + (((db * 4 + gq) ^ (row & 7)) << 3)];
                acc = __builtin_amdgcn_mfma_f32_16x16x32_bf16(qf[db], kf, acc, 0, 0, 0);
            }
            #pragma unroll
            for (int r = 0; r < 4; ++r) {
                float sv = acc[r] * 0.125f;   // 1/sqrt(64)
                if (diag) {
                    int key = k0 + ct * 16 + m;
                    int qq  = q0 + wave * 16 + gq * 4 + r;
                    if (key > qq) sv = -1e30f;
                }
                s4[ct][r] = sv;
            }
        }

        // online softmax update (rows live across 16-lane groups)
        float ps[4][4], alpha[4];
        #pragma unroll
        for (int r = 0; r < 4; ++r) {
            float v = fmaxf(fmaxf(s4[0][r], s4[1][r]), fmaxf(s4[2][r], s4[3][r]));
            v = fmaxf(v, __shfl_xor(v, 1));
            v = fmaxf(v, __shfl_xor(v, 2));
            v = fmaxf(v, __shfl_xor(v, 4));
            v = fmaxf(v, __shfl_xor(v, 8));
            float mnew = fmaxf(mrun[r], v);
            alpha[r] = __expf(mrun[r] - mnew);
            mrun[r] = mnew;
            float rsum = 0.f;
            #pragma unroll
            for (int ct = 0; ct < 4; ++ct) {
                float p = __expf(s4[ct][r] - mnew);
                ps[ct][r] = p;
                rsum += p;
            }
            rsum += __shfl_xor(rsum, 1);
            rsum += __shfl_xor(rsum, 2);
            rsum += __shfl_xor(rsum, 4);
            rsum += __shfl_xor(rsum, 8);
            lrun[r] = lrun[r] * alpha[r] + rsum;
        }
        #pragma unroll
        for (int ct2 = 0; ct2 < 4; ++ct2)
            #pragma unroll
            for (int r = 0; r < 4; ++r) o[ct2][r] *= alpha[r];

        // P (C-layout) -> LDS -> A-layout fragments (per-wave buffer)
        #pragma unroll
        for (int ct = 0; ct < 4; ++ct)
            #pragma unroll
            for (int r = 0; r < 4; ++r) {
                int row = gq * 4 + r;
                Ps[wave][row * 64 + ((((ct * 2 + (m >> 3)) ^ (row & 7)) << 3) | (m & 7))] =
                    f2bf(ps[ct][r]);
            }
        bf16x8 pf[2];
        #pragma unroll
        for (int db2 = 0; db2 < 2; ++db2)
            pf[db2] = *(const bf16x8*)&Ps[wave][m * 64 + (((db2 * 4 + gq) ^ (m & 7)) << 3)];

        #pragma unroll
        for (int ct2 = 0; ct2 < 4; ++ct2) {
            int row = ct2 * 16 + m;   // d index
            #pragma unroll
            for (int db2 = 0; db2 < 2; ++db2) {
                bf16x8 vf = *(const bf16x8*)&Vt[row * 64 + (((db2 * 4 + gq) ^ (row & 7)) << 3)];
                o[ct2] = __builtin_amdgcn_mfma_f32_16x16x32_bf16(pf[db2], vf, o[ct2], 0, 0, 0);
            }
        }
    }

    // epilogue with quirk permutation: t>>6 == qt (block-uniform)
    float inv[4];
    #pragma unroll
    for (int r = 0; r < 4; ++r) inv[r] = 1.0f / lrun[r];
    size_t base = (size_t)b * Tn * En + (size_t)h * 64 + (size_t)qt * En
                + wave * 16 + gq * 4;
    #pragma unroll
    for (int ct2 = 0; ct2 < 4; ++ct2) {
        int d = ct2 * 16 + m;
        #pragma unroll
        for (int r = 0; r < 4; ++r)
            cat[base + (size_t)d * 32 * En + r] = o[ct2][r] * inv[r];
    }
}

extern "C" void kernel_launch(void* const* d_in, const int* in_sizes, int n_in,
                              void* d_out, int out_size, void* d_ws, size_t ws_size,
                              hipStream_t stream) {
    const float* x     = (const float*)d_in[0];
    const float* Wq    = (const float*)d_in[1];
    const float* Wk    = (const float*)d_in[2];
    const float* Wv    = (const float*)d_in[3];
    const float* fc_w  = (const float*)d_in[4];
    const float* fc_b  = (const float*)d_in[5];
    const float* ln1_s = (const float*)d_in[6];
    const float* ln1_b = (const float*)d_in[7];
    const float* ln2_s = (const float*)d_in[8];
    const float* ln2_b = (const float*)d_in[9];
    const float* ff_w1 = (const float*)d_in[10];
    const float* ff_b1 = (const float*)d_in[11];
    const float* ff_w2 = (const float*)d_in[12];
    const float* ff_b2 = (const float*)d_in[13];
    float* out = (float*)d_out;
    (void)in_sizes; (void)n_in; (void)out_size; (void)ws_size;

    float* ws = (float*)d_ws;
    float* xn   = ws;               // LN1 out; dead after qkv
    float* qb   = ws + 4194304;
    float* kbuf = ws + 8388608;
    float* vbuf = ws + 12582912;
    float* cat  = ws;               // reuse xn
    float* hbuf = ws + 4194304;     // reuse qb
    float* ynb  = ws + 8388608;     // reuse kbuf
    float* y1   = ws + 12582912;    // reuse vbuf (16M floats)

    ln_kernel<<<dim3(Mrows), dim3(256), 0, stream>>>(x, ln1_s, ln1_b, xn);
    qkv_kernel<<<dim3(Mrows / 64, Hn, 3), dim3(256), 0, stream>>>(
        xn, Wq, Wk, Wv, qb, kbuf, vbuf);
    attn_mfma<<<dim3(Hn * Bn, Tn / 64), dim3(256), 0, stream>>>(
        qb, kbuf, vbuf, cat);
    gemm_kernel<0, 1><<<dim3(Mrows / 64, En / 64), dim3(256), 0, stream>>>(
        cat, En, fc_w, En, hbuf, En, En, fc_b, x);
    ln_kernel<<<dim3(Mrows), dim3(256), 0, stream>>>(hbuf, ln2_s, ln2_b, ynb);
    gemm_kernel<1, 0><<<dim3(Mrows / 64, 4 * En / 64), dim3(256), 0, stream>>>(
        ynb, En, ff_w1, 4 * En, y1, 4 * En, En, ff_b1, nullptr);
    gemm_kernel<0, 1><<<dim3(Mrows / 64, En / 64), dim3(256), 0, stream>>>(
        y1, 4 * En, ff_w2, En, out, En, 4 * En, ff_b2, hbuf);
}

// Round 4
// 454.895 us; speedup vs baseline: 6.1118x; 3.4723x over previous
//
#include <hip/hip_runtime.h>

// Transformer block. B=2 T=2048 E=1024 H=16 DH=64.
// R4: all GEMMs -> bf16 MFMA (m97 recipe: 128x128 tile, BK=32, global_load_lds
// width 16, B^T operand). Weights transposed+converted per launch; activations
// carried in bf16 between stages. Attention takes bf16 q/k/v directly.

#define En 1024
#define Hn 16
#define DHn 64
#define Bn 2
#define Tn 2048
#define Mrows 4096  // B*T

typedef __attribute__((ext_vector_type(8))) short bf16x8;
typedef __attribute__((ext_vector_type(4))) float f32x4;

__device__ __forceinline__ short f2bf(float f) {
    unsigned u = __float_as_uint(f);
    u += 0x7FFFu + ((u >> 16) & 1u);   // round-to-nearest-even
    return (short)(u >> 16);
}
__device__ __forceinline__ ushort f2bfu(float f) {
    unsigned u = __float_as_uint(f);
    u += 0x7FFFu + ((u >> 16) & 1u);
    return (ushort)(u >> 16);
}

__device__ __forceinline__ float gelu_f(float x) {
    float inner = 0.79788456080286535588f * x + 0.044715f * x * x * x;
    return 0.5f * x * (1.0f + tanhf(inner));
}

// async global->LDS, 16B per lane; LDS dest = wave-uniform base + lane*16
__device__ __forceinline__ void load_lds16(const void* g, void* l) {
    __builtin_amdgcn_global_load_lds(
        (const __attribute__((address_space(1))) unsigned int*)(uintptr_t)g,
        (__attribute__((address_space(3))) unsigned int*)(uintptr_t)l,
        16, 0, 0);
}

// ---------------- LayerNorm: one block per row, bf16 out ----------------
__global__ __launch_bounds__(256) void ln_kernel(
    const float* __restrict__ in, const float* __restrict__ sc,
    const float* __restrict__ sh, ushort* __restrict__ out)
{
    int row = blockIdx.x;
    int tid = threadIdx.x;
    float4 v = ((const float4*)(in + (size_t)row * En))[tid];
    float s  = v.x + v.y + v.z + v.w;
    float s2 = v.x*v.x + v.y*v.y + v.z*v.z + v.w*v.w;
    #pragma unroll
    for (int off = 32; off > 0; off >>= 1) {
        s  += __shfl_down(s,  off);
        s2 += __shfl_down(s2, off);
    }
    __shared__ float red[2][4];
    int wave = tid >> 6, lane = tid & 63;
    if (lane == 0) { red[0][wave] = s; red[1][wave] = s2; }
    __syncthreads();
    s  = red[0][0] + red[0][1] + red[0][2] + red[0][3];
    s2 = red[1][0] + red[1][1] + red[1][2] + red[1][3];
    float mean = s * (1.0f / En);
    float var  = s2 * (1.0f / En) - mean * mean;
    float r = rsqrtf(var + 1e-5f);
    float4 scv = ((const float4*)sc)[tid];
    float4 shv = ((const float4*)sh)[tid];
    ushort4 o;
    o.x = f2bfu(scv.x * (v.x - mean) * r + shv.x);
    o.y = f2bfu(scv.y * (v.y - mean) * r + shv.y);
    o.z = f2bfu(scv.z * (v.z - mean) * r + shv.z);
    o.w = f2bfu(scv.w * (v.w - mean) * r + shv.w);
    ((ushort4*)(out + (size_t)row * En))[tid] = o;
}

// ---------------- weight transpose+convert: out[n*K+k] = bf16(in[k*N+n]) ----
__global__ __launch_bounds__(256) void transpose_w(
    const float* __restrict__ in, ushort* __restrict__ out, int K, int N)
{
    __shared__ float t[64][65];
    int k0 = blockIdx.x * 64, n0 = blockIdx.y * 64;
    int tid = threadIdx.x, r = tid >> 4, c4 = (tid & 15) * 4;
    #pragma unroll
    for (int i = 0; i < 4; ++i) {
        float4 v = *(const float4*)(in + (size_t)(k0 + r + i * 16) * N + n0 + c4);
        t[r + i * 16][c4 + 0] = v.x; t[r + i * 16][c4 + 1] = v.y;
        t[r + i * 16][c4 + 2] = v.z; t[r + i * 16][c4 + 3] = v.w;
    }
    __syncthreads();
    #pragma unroll
    for (int i = 0; i < 4; ++i) {
        int n = r + i * 16;
        ushort4 u;
        u.x = f2bfu(t[c4 + 0][n]); u.y = f2bfu(t[c4 + 1][n]);
        u.z = f2bfu(t[c4 + 2][n]); u.w = f2bfu(t[c4 + 3][n]);
        *(ushort4*)(out + (size_t)(n0 + n) * K + k0 + c4) = u;
    }
}

// qkv weights: Wq/Wk/Wv [H][E][DH] -> combined B^T [3072][1024]
__global__ __launch_bounds__(256) void transpose_qkv(
    const float* __restrict__ Wq, const float* __restrict__ Wk,
    const float* __restrict__ Wv, ushort* __restrict__ out)
{
    __shared__ float t[64][65];
    int z = blockIdx.z, sel = z >> 4, h = z & 15;
    const float* in = (sel == 0 ? Wq : sel == 1 ? Wk : Wv) + (size_t)h * En * DHn;
    ushort* o = out + ((size_t)(sel * 1024 + h * 64)) * En;
    int k0 = blockIdx.x * 64;
    int tid = threadIdx.x, r = tid >> 4, c4 = (tid & 15) * 4;
    #pragma unroll
    for (int i = 0; i < 4; ++i) {
        float4 v = *(const float4*)(in + (size_t)(k0 + r + i * 16) * DHn + c4);
        t[r + i * 16][c4 + 0] = v.x; t[r + i * 16][c4 + 1] = v.y;
        t[r + i * 16][c4 + 2] = v.z; t[r + i * 16][c4 + 3] = v.w;
    }
    __syncthreads();
    #pragma unroll
    for (int i = 0; i < 4; ++i) {
        int n = r + i * 16;   // d index 0..63
        ushort4 u;
        u.x = f2bfu(t[c4 + 0][n]); u.y = f2bfu(t[c4 + 1][n]);
        u.z = f2bfu(t[c4 + 2][n]); u.w = f2bfu(t[c4 + 3][n]);
        *(ushort4*)(o + (size_t)n * En + k0 + c4) = u;
    }
}

// ---------------- bf16 MFMA GEMM: C[M][N] = A[M][K] * Bt[N][K]^T -----------
// MODE 0: Cf = acc + bias + resid (fp32 out)
// MODE 1: Cb = bf16(gelu(acc + bias))
// MODE 2: qkv scatter, no bias: col -> (sel,h,d); bf16 out in (h,b,t,d) layout
template<int MODE>
__global__ __launch_bounds__(256) void gemm_bf16(
    const ushort* __restrict__ A, int lda,
    const ushort* __restrict__ Bt, int K,
    const float* __restrict__ bias,
    const float* __restrict__ resid, int ldr,
    float* __restrict__ Cf, ushort* __restrict__ Cb, int ldc,
    ushort* __restrict__ qo, ushort* __restrict__ ko, ushort* __restrict__ vo)
{
    __shared__ ushort As[128 * 32];
    __shared__ ushort Bs[128 * 32];
    int tid = threadIdx.x, wv = tid >> 6, ln = tid & 63;
    int m0 = blockIdx.x * 128, n0 = blockIdx.y * 128;
    int wr = wv >> 1, wc = wv & 1;
    int hm = ln & 15, hk = ln >> 4;

    f32x4 acc[4][4];
    #pragma unroll
    for (int i = 0; i < 4; ++i)
        #pragma unroll
        for (int j = 0; j < 4; ++j) acc[i][j] = (f32x4){0.f, 0.f, 0.f, 0.f};

    const ushort* Abase = A + (size_t)m0 * lda;
    const ushort* Bbase = Bt + (size_t)n0 * K;

    for (int k0 = 0; k0 < K; k0 += 32) {
        __syncthreads();
        #pragma unroll
        for (int i = 0; i < 2; ++i) {
            int c = wv * 128 + i * 64 + ln;   // 16B chunk id; row=c>>2, kchunk=c&3
            load_lds16(Abase + (size_t)(c >> 2) * lda + k0 + (c & 3) * 8,
                       &As[(wv * 128 + i * 64) * 8]);
            load_lds16(Bbase + (size_t)(c >> 2) * K + k0 + (c & 3) * 8,
                       &Bs[(wv * 128 + i * 64) * 8]);
        }
        __syncthreads();
        bf16x8 af[4], bfr[4];
        #pragma unroll
        for (int mi = 0; mi < 4; ++mi)
            af[mi] = *(const bf16x8*)&As[(wr * 64 + mi * 16 + hm) * 32 + hk * 8];
        #pragma unroll
        for (int ni = 0; ni < 4; ++ni)
            bfr[ni] = *(const bf16x8*)&Bs[(wc * 64 + ni * 16 + hm) * 32 + hk * 8];
        #pragma unroll
        for (int mi = 0; mi < 4; ++mi)
            #pragma unroll
            for (int ni = 0; ni < 4; ++ni)
                acc[mi][ni] = __builtin_amdgcn_mfma_f32_16x16x32_bf16(
                    af[mi], bfr[ni], acc[mi][ni], 0, 0, 0);
    }

    int colbase = n0 + wc * 64 + hm;
    int rowbase = m0 + wr * 64 + hk * 4;
    if (MODE == 0) {
        #pragma unroll
        for (int ni = 0; ni < 4; ++ni) {
            int col = colbase + ni * 16;
            float bb = bias[col];
            #pragma unroll
            for (int mi = 0; mi < 4; ++mi) {
                int row = rowbase + mi * 16;
                #pragma unroll
                for (int r = 0; r < 4; ++r)
                    Cf[(size_t)(row + r) * ldc + col] =
                        acc[mi][ni][r] + bb + resid[(size_t)(row + r) * ldr + col];
            }
        }
    } else if (MODE == 1) {
        #pragma unroll
        for (int ni = 0; ni < 4; ++ni) {
            int col = colbase + ni * 16;
            float bb = bias[col];
            #pragma unroll
            for (int mi = 0; mi < 4; ++mi) {
                int row = rowbase + mi * 16;
                #pragma unroll
                for (int r = 0; r < 4; ++r)
                    Cb[(size_t)(row + r) * ldc + col] =
                        f2bfu(gelu_f(acc[mi][ni][r] + bb));
            }
        }
    } else {
        #pragma unroll
        for (int ni = 0; ni < 4; ++ni) {
            int col = colbase + ni * 16;           // 0..3071
            int sel = col >> 10, cc = col & 1023;
            int h = cc >> 6, d = cc & 63;
            ushort* outp = (sel == 0 ? qo : sel == 1 ? ko : vo)
                         + (size_t)h * (Mrows * DHn) + d;
            #pragma unroll
            for (int mi = 0; mi < 4; ++mi) {
                int row = rowbase + mi * 16;
                #pragma unroll
                for (int r = 0; r < 4; ++r)
                    outp[(size_t)(row + r) * DHn] = f2bfu(acc[mi][ni][r]);
            }
        }
    }
}

// ---------------- MFMA flash attention (bf16 q/k/v in, bf16 cat out) --------
__global__ __launch_bounds__(256) void attn_mfma(
    const ushort* __restrict__ q, const ushort* __restrict__ ksrc,
    const ushort* __restrict__ vsrc, ushort* __restrict__ cat)
{
    int g = blockIdx.x, qt = blockIdx.y;
    int h = g >> 1, b = g & 1;
    const ushort* qg = q    + (size_t)g * Tn * DHn;
    const ushort* kg = ksrc + (size_t)g * Tn * DHn;
    const ushort* vg = vsrc + (size_t)g * Tn * DHn;
    int q0 = qt * 64;
    int tid = threadIdx.x, wave = tid >> 6, lane = tid & 63;
    int m = lane & 15, gq = lane >> 4;

    __shared__ short Ks[4096];      // [key(64)][d(64)] swizzled
    __shared__ short Vt[4096];      // [d(64)][key(64)] swizzled
    __shared__ short Ps[4][1024];   // per-wave [q(16)][key(64)] swizzled

    bf16x8 qf[2];
    {
        const ushort* qp = qg + (size_t)(q0 + wave * 16 + m) * DHn + gq * 8;
        qf[0] = *(const bf16x8*)(qp);
        qf[1] = *(const bf16x8*)(qp + 32);
    }

    f32x4 o[4];
    #pragma unroll
    for (int i = 0; i < 4; ++i) o[i] = (f32x4){0.f, 0.f, 0.f, 0.f};
    float mrun[4] = {-1e30f, -1e30f, -1e30f, -1e30f};
    float lrun[4] = {0.f, 0.f, 0.f, 0.f};

    int R  = tid >> 2;
    int c2 = tid & 3;

    for (int kt = 0; kt <= qt; ++kt) {
        int k0 = kt * 64;
        __syncthreads();
        {
            const ushort* ksp = kg + (size_t)(k0 + R) * DHn + c2 * 16;
            const ushort* vsp = vg + (size_t)(k0 + R) * DHn + c2 * 16;
            bf16x8 f0 = *(const bf16x8*)(ksp);
            bf16x8 f1 = *(const bf16x8*)(ksp + 8);
            bf16x8 v0 = *(const bf16x8*)(vsp);
            bf16x8 v1 = *(const bf16x8*)(vsp + 8);
            *(bf16x8*)&Ks[R * 64 + (((c2 * 2    ) ^ (R & 7)) << 3)] = f0;
            *(bf16x8*)&Ks[R * 64 + (((c2 * 2 + 1) ^ (R & 7)) << 3)] = f1;
            #pragma unroll
            for (int i = 0; i < 8; ++i) {
                int d0 = c2 * 16 + i;
                int d1 = c2 * 16 + 8 + i;
                Vt[d0 * 64 + ((((R >> 3) ^ (d0 & 7)) << 3) | (R & 7))] = v0[i];
                Vt[d1 * 64 + ((((R >> 3) ^ (d1 & 7)) << 3) | (R & 7))] = v1[i];
            }
        }
        __syncthreads();

        bool diag = (kt == qt);
        float s4[4][4];
        #pragma unroll
        for (int ct = 0; ct < 4; ++ct) {
            if (diag && ct > wave) {
                s4[ct][0] = s4[ct][1] = s4[ct][2] = s4[ct][3] = -1e30f;
                continue;
            }
            f32x4 acc = (f32x4){0.f, 0.f, 0.f, 0.f};
            int row = ct * 16 + m;
            #pragma unroll
            for (int db = 0; db < 2; ++db) {
                bf16x8 kf = *(const bf16x8*)&Ks[row * 64 + (((db * 4 + gq) ^ (row & 7)) << 3)];
                acc = __builtin_amdgcn_mfma_f32_16x16x32_bf16(qf[db], kf, acc, 0, 0, 0);
            }
            #pragma unroll
            for (int r = 0; r < 4; ++r) {
                float sv = acc[r] * 0.125f;
                if (diag) {
                    int key = k0 + ct * 16 + m;
                    int qq  = q0 + wave * 16 + gq * 4 + r;
                    if (key > qq) sv = -1e30f;
                }
                s4[ct][r] = sv;
            }
        }

        float ps[4][4], alpha[4];
        #pragma unroll
        for (int r = 0; r < 4; ++r) {
            float v = fmaxf(fmaxf(s4[0][r], s4[1][r]), fmaxf(s4[2][r], s4[3][r]));
            v = fmaxf(v, __shfl_xor(v, 1));
            v = fmaxf(v, __shfl_xor(v, 2));
            v = fmaxf(v, __shfl_xor(v, 4));
            v = fmaxf(v, __shfl_xor(v, 8));
            float mnew = fmaxf(mrun[r], v);
            alpha[r] = __expf(mrun[r] - mnew);
            mrun[r] = mnew;
            float rsum = 0.f;
            #pragma unroll
            for (int ct = 0; ct < 4; ++ct) {
                float p = __expf(s4[ct][r] - mnew);
                ps[ct][r] = p;
                rsum += p;
            }
            rsum += __shfl_xor(rsum, 1);
            rsum += __shfl_xor(rsum, 2);
            rsum += __shfl_xor(rsum, 4);
            rsum += __shfl_xor(rsum, 8);
            lrun[r] = lrun[r] * alpha[r] + rsum;
        }
        #pragma unroll
        for (int ct2 = 0; ct2 < 4; ++ct2)
            #pragma unroll
            for (int r = 0; r < 4; ++r) o[ct2][r] *= alpha[r];

        #pragma unroll
        for (int ct = 0; ct < 4; ++ct)
            #pragma unroll
            for (int r = 0; r < 4; ++r) {
                int row = gq * 4 + r;
                Ps[wave][row * 64 + ((((ct * 2 + (m >> 3)) ^ (row & 7)) << 3) | (m & 7))] =
                    f2bf(ps[ct][r]);
            }
        bf16x8 pf[2];
        #pragma unroll
        for (int db2 = 0; db2 < 2; ++db2)
            pf[db2] = *(const bf16x8*)&Ps[wave][m * 64 + (((db2 * 4 + gq) ^ (m & 7)) << 3)];

        #pragma unroll
        for (int ct2 = 0; ct2 < 4; ++ct2) {
            int row = ct2 * 16 + m;
            #pragma unroll
            for (int db2 = 0; db2 < 2; ++db2) {
                bf16x8 vf = *(const bf16x8*)&Vt[row * 64 + (((db2 * 4 + gq) ^ (row & 7)) << 3)];
                o[ct2] = __builtin_amdgcn_mfma_f32_16x16x32_bf16(pf[db2], vf, o[ct2], 0, 0, 0);
            }
        }
    }

    float inv[4];
    #pragma unroll
    for (int r = 0; r < 4; ++r) inv[r] = 1.0f / lrun[r];
    size_t base = (size_t)b * Tn * En + (size_t)h * 64 + (size_t)qt * En
                + wave * 16 + gq * 4;
    #pragma unroll
    for (int ct2 = 0; ct2 < 4; ++ct2) {
        int d = ct2 * 16 + m;
        #pragma unroll
        for (int r = 0; r < 4; ++r)
            cat[base + (size_t)d * 32 * En + r] = f2bfu(o[ct2][r] * inv[r]);
    }
}

extern "C" void kernel_launch(void* const* d_in, const int* in_sizes, int n_in,
                              void* d_out, int out_size, void* d_ws, size_t ws_size,
                              hipStream_t stream) {
    const float* x     = (const float*)d_in[0];
    const float* Wq    = (const float*)d_in[1];
    const float* Wk    = (const float*)d_in[2];
    const float* Wv    = (const float*)d_in[3];
    const float* fc_w  = (const float*)d_in[4];
    const float* fc_b  = (const float*)d_in[5];
    const float* ln1_s = (const float*)d_in[6];
    const float* ln1_b = (const float*)d_in[7];
    const float* ln2_s = (const float*)d_in[8];
    const float* ln2_b = (const float*)d_in[9];
    const float* ff_w1 = (const float*)d_in[10];
    const float* ff_b1 = (const float*)d_in[11];
    const float* ff_w2 = (const float*)d_in[12];
    const float* ff_b2 = (const float*)d_in[13];
    float* out = (float*)d_out;
    (void)in_sizes; (void)n_in; (void)out_size; (void)ws_size;

    const size_t MB = 1048576;
    char* w8 = (char*)d_ws;
    ushort* S0   = (ushort*)(w8 + 0 * MB);    // xn_bf / cat_bf (8MB)
    ushort* kb   = (ushort*)(w8 + 8 * MB);    // k bf16 (8MB)
    ushort* vb   = (ushort*)(w8 + 16 * MB);   // v bf16 (8MB)
    ushort* qb   = (ushort*)(w8 + 24 * MB);   // q bf16 / ynb_bf (8MB)
    float*  hb   = (float*)(w8 + 32 * MB);    // h fp32 (16MB)
    ushort* y1   = (ushort*)(w8 + 48 * MB);   // gelu out bf16 [4096][4096] (32MB)
    ushort* wqkv = (ushort*)(w8 + 80 * MB);   // [3072][1024] (6MB)
    ushort* wfc  = (ushort*)(w8 + 86 * MB);   // [1024][1024] (2MB)
    ushort* wf1  = (ushort*)(w8 + 88 * MB);   // [4096][1024] (8MB)
    ushort* wf2  = (ushort*)(w8 + 96 * MB);   // [1024][4096] (8MB) -> 104MB total

    // weight prep
    transpose_qkv<<<dim3(16, 1, 48), 256, 0, stream>>>(Wq, Wk, Wv, wqkv);
    transpose_w<<<dim3(16, 16), 256, 0, stream>>>(fc_w, wfc, En, En);
    transpose_w<<<dim3(16, 64), 256, 0, stream>>>(ff_w1, wf1, En, 4 * En);
    transpose_w<<<dim3(64, 16), 256, 0, stream>>>(ff_w2, wf2, 4 * En, En);

    // LN1 -> xn (bf16)
    ln_kernel<<<dim3(Mrows), 256, 0, stream>>>(x, ln1_s, ln1_b, S0);
    // QKV: [4096,1024] x [3072,1024]^T, scatter epilogue
    gemm_bf16<2><<<dim3(32, 24), 256, 0, stream>>>(
        S0, En, wqkv, En, nullptr, nullptr, 0, nullptr, nullptr, 0, qb, kb, vb);
    // attention -> cat (bf16, quirk layout), reuses S0
    attn_mfma<<<dim3(Hn * Bn, Tn / 64), 256, 0, stream>>>(qb, kb, vb, S0);
    // fc: h = cat @ fc_w + fc_b + x  (fp32 out)
    gemm_bf16<0><<<dim3(32, 8), 256, 0, stream>>>(
        S0, En, wfc, En, fc_b, x, En, hb, nullptr, En, nullptr, nullptr, nullptr);
    // LN2 -> ynb (bf16, reuses qb)
    ln_kernel<<<dim3(Mrows), 256, 0, stream>>>(hb, ln2_s, ln2_b, qb);
    // ff1: y1 = gelu(ynb @ ff_w1 + ff_b1)  (bf16 out)
    gemm_bf16<1><<<dim3(32, 32), 256, 0, stream>>>(
        qb, En, wf1, En, ff_b1, nullptr, 0, nullptr, y1, 4 * En, nullptr, nullptr, nullptr);
    // ff2: out = y1 @ ff_w2 + ff_b2 + h  (fp32 out)
    gemm_bf16<0><<<dim3(32, 8), 256, 0, stream>>>(
        y1, 4 * En, wf2, 4 * En, ff_b2, hb, En, out, nullptr, En, nullptr, nullptr, nullptr);
}

// Round 5
// 408.218 us; speedup vs baseline: 6.8106x; 1.1143x over previous
//
#include <hip/hip_runtime.h>

// Transformer block. B=2 T=2048 E=1024 H=16 DH=64.
// R5: attention v3 — fixed-base softmax (no running max; logits bounded ~2),
// global V^T layout (vectorized LDS staging, no scatter conflicts), uniform
// work pairing (block does qt and 31-qt: exactly 33 key-tiles each).
// GEMMs unchanged from R4 (bf16 MFMA, 128x128, global_load_lds w16).

#define En 1024
#define Hn 16
#define DHn 64
#define Bn 2
#define Tn 2048
#define Mrows 4096  // B*T

typedef __attribute__((ext_vector_type(8))) short bf16x8;
typedef __attribute__((ext_vector_type(4))) float f32x4;

__device__ __forceinline__ short f2bf(float f) {
    unsigned u = __float_as_uint(f);
    u += 0x7FFFu + ((u >> 16) & 1u);   // round-to-nearest-even
    return (short)(u >> 16);
}
__device__ __forceinline__ ushort f2bfu(float f) {
    unsigned u = __float_as_uint(f);
    u += 0x7FFFu + ((u >> 16) & 1u);
    return (ushort)(u >> 16);
}

__device__ __forceinline__ float gelu_f(float x) {
    float inner = 0.79788456080286535588f * x + 0.044715f * x * x * x;
    return 0.5f * x * (1.0f + tanhf(inner));
}

// async global->LDS, 16B per lane; LDS dest = wave-uniform base + lane*16
__device__ __forceinline__ void load_lds16(const void* g, void* l) {
    __builtin_amdgcn_global_load_lds(
        (const __attribute__((address_space(1))) unsigned int*)(uintptr_t)g,
        (__attribute__((address_space(3))) unsigned int*)(uintptr_t)l,
        16, 0, 0);
}

// ---------------- LayerNorm: one block per row, bf16 out ----------------
__global__ __launch_bounds__(256) void ln_kernel(
    const float* __restrict__ in, const float* __restrict__ sc,
    const float* __restrict__ sh, ushort* __restrict__ out)
{
    int row = blockIdx.x;
    int tid = threadIdx.x;
    float4 v = ((const float4*)(in + (size_t)row * En))[tid];
    float s  = v.x + v.y + v.z + v.w;
    float s2 = v.x*v.x + v.y*v.y + v.z*v.z + v.w*v.w;
    #pragma unroll
    for (int off = 32; off > 0; off >>= 1) {
        s  += __shfl_down(s,  off);
        s2 += __shfl_down(s2, off);
    }
    __shared__ float red[2][4];
    int wave = tid >> 6, lane = tid & 63;
    if (lane == 0) { red[0][wave] = s; red[1][wave] = s2; }
    __syncthreads();
    s  = red[0][0] + red[0][1] + red[0][2] + red[0][3];
    s2 = red[1][0] + red[1][1] + red[1][2] + red[1][3];
    float mean = s * (1.0f / En);
    float var  = s2 * (1.0f / En) - mean * mean;
    float r = rsqrtf(var + 1e-5f);
    float4 scv = ((const float4*)sc)[tid];
    float4 shv = ((const float4*)sh)[tid];
    ushort4 o;
    o.x = f2bfu(scv.x * (v.x - mean) * r + shv.x);
    o.y = f2bfu(scv.y * (v.y - mean) * r + shv.y);
    o.z = f2bfu(scv.z * (v.z - mean) * r + shv.z);
    o.w = f2bfu(scv.w * (v.w - mean) * r + shv.w);
    ((ushort4*)(out + (size_t)row * En))[tid] = o;
}

// ---------------- weight transpose+convert: out[n*K+k] = bf16(in[k*N+n]) ----
__global__ __launch_bounds__(256) void transpose_w(
    const float* __restrict__ in, ushort* __restrict__ out, int K, int N)
{
    __shared__ float t[64][65];
    int k0 = blockIdx.x * 64, n0 = blockIdx.y * 64;
    int tid = threadIdx.x, r = tid >> 4, c4 = (tid & 15) * 4;
    #pragma unroll
    for (int i = 0; i < 4; ++i) {
        float4 v = *(const float4*)(in + (size_t)(k0 + r + i * 16) * N + n0 + c4);
        t[r + i * 16][c4 + 0] = v.x; t[r + i * 16][c4 + 1] = v.y;
        t[r + i * 16][c4 + 2] = v.z; t[r + i * 16][c4 + 3] = v.w;
    }
    __syncthreads();
    #pragma unroll
    for (int i = 0; i < 4; ++i) {
        int n = r + i * 16;
        ushort4 u;
        u.x = f2bfu(t[c4 + 0][n]); u.y = f2bfu(t[c4 + 1][n]);
        u.z = f2bfu(t[c4 + 2][n]); u.w = f2bfu(t[c4 + 3][n]);
        *(ushort4*)(out + (size_t)(n0 + n) * K + k0 + c4) = u;
    }
}

// qkv weights: Wq/Wk/Wv [H][E][DH] -> combined B^T [3072][1024]
__global__ __launch_bounds__(256) void transpose_qkv(
    const float* __restrict__ Wq, const float* __restrict__ Wk,
    const float* __restrict__ Wv, ushort* __restrict__ out)
{
    __shared__ float t[64][65];
    int z = blockIdx.z, sel = z >> 4, h = z & 15;
    const float* in = (sel == 0 ? Wq : sel == 1 ? Wk : Wv) + (size_t)h * En * DHn;
    ushort* o = out + ((size_t)(sel * 1024 + h * 64)) * En;
    int k0 = blockIdx.x * 64;
    int tid = threadIdx.x, r = tid >> 4, c4 = (tid & 15) * 4;
    #pragma unroll
    for (int i = 0; i < 4; ++i) {
        float4 v = *(const float4*)(in + (size_t)(k0 + r + i * 16) * DHn + c4);
        t[r + i * 16][c4 + 0] = v.x; t[r + i * 16][c4 + 1] = v.y;
        t[r + i * 16][c4 + 2] = v.z; t[r + i * 16][c4 + 3] = v.w;
    }
    __syncthreads();
    #pragma unroll
    for (int i = 0; i < 4; ++i) {
        int n = r + i * 16;   // d index 0..63
        ushort4 u;
        u.x = f2bfu(t[c4 + 0][n]); u.y = f2bfu(t[c4 + 1][n]);
        u.z = f2bfu(t[c4 + 2][n]); u.w = f2bfu(t[c4 + 3][n]);
        *(ushort4*)(o + (size_t)n * En + k0 + c4) = u;
    }
}

// ---------------- bf16 MFMA GEMM: C[M][N] = A[M][K] * Bt[N][K]^T -----------
// MODE 0: Cf = acc + bias + resid (fp32 out)
// MODE 1: Cb = bf16(gelu(acc + bias))
// MODE 2: qkv scatter, no bias: col -> (sel,h,d); q/k in (h,b,t,d) layout,
//         v transposed: vt[(h*2+b)*64 + d][t] (packed 8B stores)
template<int MODE>
__global__ __launch_bounds__(256) void gemm_bf16(
    const ushort* __restrict__ A, int lda,
    const ushort* __restrict__ Bt, int K,
    const float* __restrict__ bias,
    const float* __restrict__ resid, int ldr,
    float* __restrict__ Cf, ushort* __restrict__ Cb, int ldc,
    ushort* __restrict__ qo, ushort* __restrict__ ko, ushort* __restrict__ vo)
{
    __shared__ ushort As[128 * 32];
    __shared__ ushort Bs[128 * 32];
    int tid = threadIdx.x, wv = tid >> 6, ln = tid & 63;
    int m0 = blockIdx.x * 128, n0 = blockIdx.y * 128;
    int wr = wv >> 1, wc = wv & 1;
    int hm = ln & 15, hk = ln >> 4;

    f32x4 acc[4][4];
    #pragma unroll
    for (int i = 0; i < 4; ++i)
        #pragma unroll
        for (int j = 0; j < 4; ++j) acc[i][j] = (f32x4){0.f, 0.f, 0.f, 0.f};

    const ushort* Abase = A + (size_t)m0 * lda;
    const ushort* Bbase = Bt + (size_t)n0 * K;

    for (int k0 = 0; k0 < K; k0 += 32) {
        __syncthreads();
        #pragma unroll
        for (int i = 0; i < 2; ++i) {
            int c = wv * 128 + i * 64 + ln;   // 16B chunk id; row=c>>2, kchunk=c&3
            load_lds16(Abase + (size_t)(c >> 2) * lda + k0 + (c & 3) * 8,
                       &As[(wv * 128 + i * 64) * 8]);
            load_lds16(Bbase + (size_t)(c >> 2) * K + k0 + (c & 3) * 8,
                       &Bs[(wv * 128 + i * 64) * 8]);
        }
        __syncthreads();
        bf16x8 af[4], bfr[4];
        #pragma unroll
        for (int mi = 0; mi < 4; ++mi)
            af[mi] = *(const bf16x8*)&As[(wr * 64 + mi * 16 + hm) * 32 + hk * 8];
        #pragma unroll
        for (int ni = 0; ni < 4; ++ni)
            bfr[ni] = *(const bf16x8*)&Bs[(wc * 64 + ni * 16 + hm) * 32 + hk * 8];
        #pragma unroll
        for (int mi = 0; mi < 4; ++mi)
            #pragma unroll
            for (int ni = 0; ni < 4; ++ni)
                acc[mi][ni] = __builtin_amdgcn_mfma_f32_16x16x32_bf16(
                    af[mi], bfr[ni], acc[mi][ni], 0, 0, 0);
    }

    int colbase = n0 + wc * 64 + hm;
    int rowbase = m0 + wr * 64 + hk * 4;
    if (MODE == 0) {
        #pragma unroll
        for (int ni = 0; ni < 4; ++ni) {
            int col = colbase + ni * 16;
            float bb = bias[col];
            #pragma unroll
            for (int mi = 0; mi < 4; ++mi) {
                int row = rowbase + mi * 16;
                #pragma unroll
                for (int r = 0; r < 4; ++r)
                    Cf[(size_t)(row + r) * ldc + col] =
                        acc[mi][ni][r] + bb + resid[(size_t)(row + r) * ldr + col];
            }
        }
    } else if (MODE == 1) {
        #pragma unroll
        for (int ni = 0; ni < 4; ++ni) {
            int col = colbase + ni * 16;
            float bb = bias[col];
            #pragma unroll
            for (int mi = 0; mi < 4; ++mi) {
                int row = rowbase + mi * 16;
                #pragma unroll
                for (int r = 0; r < 4; ++r)
                    Cb[(size_t)(row + r) * ldc + col] =
                        f2bfu(gelu_f(acc[mi][ni][r] + bb));
            }
        }
    } else {
        #pragma unroll
        for (int ni = 0; ni < 4; ++ni) {
            int col = colbase + ni * 16;           // 0..3071
            int sel = col >> 10, cc = col & 1023;
            int h = cc >> 6, d = cc & 63;
            if (sel < 2) {
                ushort* outp = (sel == 0 ? qo : ko)
                             + (size_t)h * (Mrows * DHn) + d;
                #pragma unroll
                for (int mi = 0; mi < 4; ++mi) {
                    int row = rowbase + mi * 16;
                    #pragma unroll
                    for (int r = 0; r < 4; ++r)
                        outp[(size_t)(row + r) * DHn] = f2bfu(acc[mi][ni][r]);
                }
            } else {
                // v transposed: vt[(h*2+b)*64 + d][t], t = row & 2047
                #pragma unroll
                for (int mi = 0; mi < 4; ++mi) {
                    int row = rowbase + mi * 16;
                    int bb2 = row >> 11, t = row & 2047;
                    ushort4 u;
                    u.x = f2bfu(acc[mi][ni][0]); u.y = f2bfu(acc[mi][ni][1]);
                    u.z = f2bfu(acc[mi][ni][2]); u.w = f2bfu(acc[mi][ni][3]);
                    *(ushort4*)(vo + ((size_t)((h * 2 + bb2) * 64 + d)) * Tn + t) = u;
                }
            }
        }
    }
}

// ---------------- MFMA flash attention v3 ----------------
// grid (32 g, 16 pairs); block processes qt = y and qt = 31-y (33 tiles total).
// Fixed-base softmax: p = exp(logit) (logits bounded ~2), l reduced in epilogue.
// K row-major [t][d]; V pre-transposed globally [d][t]; both staged with
// vectorized XOR-swizzled b128 stores (conflict-free).
__global__ __launch_bounds__(256) void attn_mfma(
    const ushort* __restrict__ q, const ushort* __restrict__ ksrc,
    const ushort* __restrict__ vtsrc, ushort* __restrict__ cat)
{
    int g = blockIdx.x;
    int h = g >> 1, b = g & 1;
    const ushort* qg  = q     + (size_t)g * Tn * DHn;
    const ushort* kg  = ksrc  + (size_t)g * Tn * DHn;
    const ushort* vtg = vtsrc + (size_t)g * DHn * Tn;   // [d][t]
    int tid = threadIdx.x, wave = tid >> 6, lane = tid & 63;
    int m = lane & 15, gq = lane >> 4;

    __shared__ short Ks[4096];      // [key(64)][d(64)] swizzled
    __shared__ short Vt[4096];      // [d(64)][key(64)] swizzled
    __shared__ short Ps[4][1024];   // per-wave [q(16)][key(64)] swizzled

    int R  = tid >> 2;   // staging row 0..63
    int c2 = tid & 3;    // staging 16-elem chunk

    #pragma unroll 1
    for (int phase = 0; phase < 2; ++phase) {
        int qt = phase ? (31 - (int)blockIdx.y) : (int)blockIdx.y;
        int q0 = qt * 64;

        bf16x8 qf[2];
        {
            const ushort* qp = qg + (size_t)(q0 + wave * 16 + m) * DHn + gq * 8;
            qf[0] = *(const bf16x8*)(qp);
            qf[1] = *(const bf16x8*)(qp + 32);
        }
        f32x4 o[4];
        #pragma unroll
        for (int i = 0; i < 4; ++i) o[i] = (f32x4){0.f, 0.f, 0.f, 0.f};
        float lsum[4] = {0.f, 0.f, 0.f, 0.f};

        for (int kt = 0; kt <= qt; ++kt) {
            int k0 = kt * 64;
            __syncthreads();
            {   // stage K tile [key][d] and V^T tile [d][key], both b128 swizzled
                const ushort* ksp = kg  + (size_t)(k0 + R) * DHn + c2 * 16;
                const ushort* vsp = vtg + (size_t)R * Tn + k0 + c2 * 16;
                bf16x8 f0 = *(const bf16x8*)(ksp);
                bf16x8 f1 = *(const bf16x8*)(ksp + 8);
                bf16x8 v0 = *(const bf16x8*)(vsp);
                bf16x8 v1 = *(const bf16x8*)(vsp + 8);
                *(bf16x8*)&Ks[R * 64 + (((c2 * 2    ) ^ (R & 7)) << 3)] = f0;
                *(bf16x8*)&Ks[R * 64 + (((c2 * 2 + 1) ^ (R & 7)) << 3)] = f1;
                *(bf16x8*)&Vt[R * 64 + (((c2 * 2    ) ^ (R & 7)) << 3)] = v0;
                *(bf16x8*)&Vt[R * 64 + (((c2 * 2 + 1) ^ (R & 7)) << 3)] = v1;
            }
            __syncthreads();

            bool diag = (kt == qt);
            float ps[4][4];
            #pragma unroll
            for (int ct = 0; ct < 4; ++ct) {
                if (diag && ct > wave) {   // fully masked sub-tile
                    ps[ct][0] = ps[ct][1] = ps[ct][2] = ps[ct][3] = 0.f;
                    continue;
                }
                f32x4 acc = (f32x4){0.f, 0.f, 0.f, 0.f};
                int row = ct * 16 + m;     // key within tile
                #pragma unroll
                for (int db = 0; db < 2; ++db) {
                    bf16x8 kf = *(const bf16x8*)&Ks[row * 64 + (((db * 4 + gq) ^ (row & 7)) << 3)];
                    acc = __builtin_amdgcn_mfma_f32_16x16x32_bf16(qf[db], kf, acc, 0, 0, 0);
                }
                #pragma unroll
                for (int r = 0; r < 4; ++r) {
                    float p;
                    if (diag && (ct * 16 + m) > (wave * 16 + gq * 4 + r)) {
                        p = 0.f;
                    } else {
                        p = __expf(acc[r] * 0.125f);   // 1/sqrt(64)
                    }
                    ps[ct][r] = p;
                    lsum[r] += p;
                }
            }

            // P (C-layout) -> LDS -> A-layout fragments (per-wave buffer)
            #pragma unroll
            for (int ct = 0; ct < 4; ++ct)
                #pragma unroll
                for (int r = 0; r < 4; ++r) {
                    int row = gq * 4 + r;
                    Ps[wave][row * 64 + ((((ct * 2 + (m >> 3)) ^ (row & 7)) << 3) | (m & 7))] =
                        f2bf(ps[ct][r]);
                }
            bf16x8 pf[2];
            #pragma unroll
            for (int db2 = 0; db2 < 2; ++db2)
                pf[db2] = *(const bf16x8*)&Ps[wave][m * 64 + (((db2 * 4 + gq) ^ (m & 7)) << 3)];

            #pragma unroll
            for (int ct2 = 0; ct2 < 4; ++ct2) {
                int row = ct2 * 16 + m;   // d index
                #pragma unroll
                for (int db2 = 0; db2 < 2; ++db2) {
                    bf16x8 vf = *(const bf16x8*)&Vt[row * 64 + (((db2 * 4 + gq) ^ (row & 7)) << 3)];
                    o[ct2] = __builtin_amdgcn_mfma_f32_16x16x32_bf16(pf[db2], vf, o[ct2], 0, 0, 0);
                }
            }
        }

        // epilogue: reduce l across the 16-lane row group, scale, quirk write
        float inv[4];
        #pragma unroll
        for (int r = 0; r < 4; ++r) {
            float l = lsum[r];
            l += __shfl_xor(l, 1);
            l += __shfl_xor(l, 2);
            l += __shfl_xor(l, 4);
            l += __shfl_xor(l, 8);
            inv[r] = 1.0f / l;
        }
        size_t base = (size_t)b * Tn * En + (size_t)h * 64 + (size_t)qt * En
                    + wave * 16 + gq * 4;
        #pragma unroll
        for (int ct2 = 0; ct2 < 4; ++ct2) {
            int d = ct2 * 16 + m;
            #pragma unroll
            for (int r = 0; r < 4; ++r)
                cat[base + (size_t)d * 32 * En + r] = f2bfu(o[ct2][r] * inv[r]);
        }
    }
}

extern "C" void kernel_launch(void* const* d_in, const int* in_sizes, int n_in,
                              void* d_out, int out_size, void* d_ws, size_t ws_size,
                              hipStream_t stream) {
    const float* x     = (const float*)d_in[0];
    const float* Wq    = (const float*)d_in[1];
    const float* Wk    = (const float*)d_in[2];
    const float* Wv    = (const float*)d_in[3];
    const float* fc_w  = (const float*)d_in[4];
    const float* fc_b  = (const float*)d_in[5];
    const float* ln1_s = (const float*)d_in[6];
    const float* ln1_b = (const float*)d_in[7];
    const float* ln2_s = (const float*)d_in[8];
    const float* ln2_b = (const float*)d_in[9];
    const float* ff_w1 = (const float*)d_in[10];
    const float* ff_b1 = (const float*)d_in[11];
    const float* ff_w2 = (const float*)d_in[12];
    const float* ff_b2 = (const float*)d_in[13];
    float* out = (float*)d_out;
    (void)in_sizes; (void)n_in; (void)out_size; (void)ws_size;

    const size_t MB = 1048576;
    char* w8 = (char*)d_ws;
    ushort* S0   = (ushort*)(w8 + 0 * MB);    // xn_bf / cat_bf (8MB)
    ushort* kb   = (ushort*)(w8 + 8 * MB);    // k bf16 (8MB)
    ushort* vtb  = (ushort*)(w8 + 16 * MB);   // v^T bf16 [g][d][t] (8MB)
    ushort* qb   = (ushort*)(w8 + 24 * MB);   // q bf16 / ynb_bf (8MB)
    float*  hb   = (float*)(w8 + 32 * MB);    // h fp32 (16MB)
    ushort* y1   = (ushort*)(w8 + 48 * MB);   // gelu out bf16 [4096][4096] (32MB)
    ushort* wqkv = (ushort*)(w8 + 80 * MB);   // [3072][1024] (6MB)
    ushort* wfc  = (ushort*)(w8 + 86 * MB);   // [1024][1024] (2MB)
    ushort* wf1  = (ushort*)(w8 + 88 * MB);   // [4096][1024] (8MB)
    ushort* wf2  = (ushort*)(w8 + 96 * MB);   // [1024][4096] (8MB) -> 104MB total

    // weight prep
    transpose_qkv<<<dim3(16, 1, 48), 256, 0, stream>>>(Wq, Wk, Wv, wqkv);
    transpose_w<<<dim3(16, 16), 256, 0, stream>>>(fc_w, wfc, En, En);
    transpose_w<<<dim3(16, 64), 256, 0, stream>>>(ff_w1, wf1, En, 4 * En);
    transpose_w<<<dim3(64, 16), 256, 0, stream>>>(ff_w2, wf2, 4 * En, En);

    // LN1 -> xn (bf16)
    ln_kernel<<<dim3(Mrows), 256, 0, stream>>>(x, ln1_s, ln1_b, S0);
    // QKV: [4096,1024] x [3072,1024]^T, scatter epilogue (v transposed)
    gemm_bf16<2><<<dim3(32, 24), 256, 0, stream>>>(
        S0, En, wqkv, En, nullptr, nullptr, 0, nullptr, nullptr, 0, qb, kb, vtb);
    // attention -> cat (bf16, quirk layout), reuses S0
    attn_mfma<<<dim3(Hn * Bn, 16), 256, 0, stream>>>(qb, kb, vtb, S0);
    // fc: h = cat @ fc_w + fc_b + x  (fp32 out)
    gemm_bf16<0><<<dim3(32, 8), 256, 0, stream>>>(
        S0, En, wfc, En, fc_b, x, En, hb, nullptr, En, nullptr, nullptr, nullptr);
    // LN2 -> ynb (bf16, reuses qb)
    ln_kernel<<<dim3(Mrows), 256, 0, stream>>>(hb, ln2_s, ln2_b, qb);
    // ff1: y1 = gelu(ynb @ ff_w1 + ff_b1)  (bf16 out)
    gemm_bf16<1><<<dim3(32, 32), 256, 0, stream>>>(
        qb, En, wf1, En, ff_b1, nullptr, 0, nullptr, y1, 4 * En, nullptr, nullptr, nullptr);
    // ff2: out = y1 @ ff_w2 + ff_b2 + h  (fp32 out)
    gemm_bf16<0><<<dim3(32, 8), 256, 0, stream>>>(
        y1, 4 * En, wf2, 4 * En, ff_b2, hb, En, out, nullptr, En, nullptr, nullptr, nullptr);
}

// Round 6
// 405.507 us; speedup vs baseline: 6.8562x; 1.0067x over previous
//
#include <hip/hip_runtime.h>

// Transformer block. B=2 T=2048 E=1024 H=16 DH=64.
// R6: GEMM fixes — (1) XOR-swizzled LDS (source-permuted global_load_lds,
// conflict-free fragment reads); (2) 128x64 tiles for N=1024 GEMMs (fc, ff2)
// giving 512 blocks = 2 blocks/CU to overlap the barrier drain.
// Attention unchanged from R5.

#define En 1024
#define Hn 16
#define DHn 64
#define Bn 2
#define Tn 2048
#define Mrows 4096  // B*T

typedef __attribute__((ext_vector_type(8))) short bf16x8;
typedef __attribute__((ext_vector_type(4))) float f32x4;

__device__ __forceinline__ short f2bf(float f) {
    unsigned u = __float_as_uint(f);
    u += 0x7FFFu + ((u >> 16) & 1u);   // round-to-nearest-even
    return (short)(u >> 16);
}
__device__ __forceinline__ ushort f2bfu(float f) {
    unsigned u = __float_as_uint(f);
    u += 0x7FFFu + ((u >> 16) & 1u);
    return (ushort)(u >> 16);
}

__device__ __forceinline__ float gelu_f(float x) {
    float inner = 0.79788456080286535588f * x + 0.044715f * x * x * x;
    return 0.5f * x * (1.0f + tanhf(inner));
}

// async global->LDS, 16B per lane; LDS dest = wave-uniform base + lane*16
__device__ __forceinline__ void load_lds16(const void* g, void* l) {
    __builtin_amdgcn_global_load_lds(
        (const __attribute__((address_space(1))) unsigned int*)(uintptr_t)g,
        (__attribute__((address_space(3))) unsigned int*)(uintptr_t)l,
        16, 0, 0);
}

// swizzled chunk offset (in ushorts): row r, 16B-chunk j
__device__ __forceinline__ int sw_off(int r, int j) {
    return (r * 4 + ((j ^ (r ^ (r >> 2))) & 3)) * 8;
}

// ---------------- LayerNorm: one block per row, bf16 out ----------------
__global__ __launch_bounds__(256) void ln_kernel(
    const float* __restrict__ in, const float* __restrict__ sc,
    const float* __restrict__ sh, ushort* __restrict__ out)
{
    int row = blockIdx.x;
    int tid = threadIdx.x;
    float4 v = ((const float4*)(in + (size_t)row * En))[tid];
    float s  = v.x + v.y + v.z + v.w;
    float s2 = v.x*v.x + v.y*v.y + v.z*v.z + v.w*v.w;
    #pragma unroll
    for (int off = 32; off > 0; off >>= 1) {
        s  += __shfl_down(s,  off);
        s2 += __shfl_down(s2, off);
    }
    __shared__ float red[2][4];
    int wave = tid >> 6, lane = tid & 63;
    if (lane == 0) { red[0][wave] = s; red[1][wave] = s2; }
    __syncthreads();
    s  = red[0][0] + red[0][1] + red[0][2] + red[0][3];
    s2 = red[1][0] + red[1][1] + red[1][2] + red[1][3];
    float mean = s * (1.0f / En);
    float var  = s2 * (1.0f / En) - mean * mean;
    float r = rsqrtf(var + 1e-5f);
    float4 scv = ((const float4*)sc)[tid];
    float4 shv = ((const float4*)sh)[tid];
    ushort4 o;
    o.x = f2bfu(scv.x * (v.x - mean) * r + shv.x);
    o.y = f2bfu(scv.y * (v.y - mean) * r + shv.y);
    o.z = f2bfu(scv.z * (v.z - mean) * r + shv.z);
    o.w = f2bfu(scv.w * (v.w - mean) * r + shv.w);
    ((ushort4*)(out + (size_t)row * En))[tid] = o;
}

// ---------------- weight transpose+convert: out[n*K+k] = bf16(in[k*N+n]) ----
__global__ __launch_bounds__(256) void transpose_w(
    const float* __restrict__ in, ushort* __restrict__ out, int K, int N)
{
    __shared__ float t[64][65];
    int k0 = blockIdx.x * 64, n0 = blockIdx.y * 64;
    int tid = threadIdx.x, r = tid >> 4, c4 = (tid & 15) * 4;
    #pragma unroll
    for (int i = 0; i < 4; ++i) {
        float4 v = *(const float4*)(in + (size_t)(k0 + r + i * 16) * N + n0 + c4);
        t[r + i * 16][c4 + 0] = v.x; t[r + i * 16][c4 + 1] = v.y;
        t[r + i * 16][c4 + 2] = v.z; t[r + i * 16][c4 + 3] = v.w;
    }
    __syncthreads();
    #pragma unroll
    for (int i = 0; i < 4; ++i) {
        int n = r + i * 16;
        ushort4 u;
        u.x = f2bfu(t[c4 + 0][n]); u.y = f2bfu(t[c4 + 1][n]);
        u.z = f2bfu(t[c4 + 2][n]); u.w = f2bfu(t[c4 + 3][n]);
        *(ushort4*)(out + (size_t)(n0 + n) * K + k0 + c4) = u;
    }
}

// qkv weights: Wq/Wk/Wv [H][E][DH] -> combined B^T [3072][1024]
__global__ __launch_bounds__(256) void transpose_qkv(
    const float* __restrict__ Wq, const float* __restrict__ Wk,
    const float* __restrict__ Wv, ushort* __restrict__ out)
{
    __shared__ float t[64][65];
    int z = blockIdx.z, sel = z >> 4, h = z & 15;
    const float* in = (sel == 0 ? Wq : sel == 1 ? Wk : Wv) + (size_t)h * En * DHn;
    ushort* o = out + ((size_t)(sel * 1024 + h * 64)) * En;
    int k0 = blockIdx.x * 64;
    int tid = threadIdx.x, r = tid >> 4, c4 = (tid & 15) * 4;
    #pragma unroll
    for (int i = 0; i < 4; ++i) {
        float4 v = *(const float4*)(in + (size_t)(k0 + r + i * 16) * DHn + c4);
        t[r + i * 16][c4 + 0] = v.x; t[r + i * 16][c4 + 1] = v.y;
        t[r + i * 16][c4 + 2] = v.z; t[r + i * 16][c4 + 3] = v.w;
    }
    __syncthreads();
    #pragma unroll
    for (int i = 0; i < 4; ++i) {
        int n = r + i * 16;   // d index 0..63
        ushort4 u;
        u.x = f2bfu(t[c4 + 0][n]); u.y = f2bfu(t[c4 + 1][n]);
        u.z = f2bfu(t[c4 + 2][n]); u.w = f2bfu(t[c4 + 3][n]);
        *(ushort4*)(o + (size_t)n * En + k0 + c4) = u;
    }
}

// ---------------- bf16 MFMA GEMM: C[M][N] = A[M][K] * Bt[N][K]^T -----------
// 128 x TN tile (TN = 64 or 128), BK=32, 4 waves in 2x2.
// MODE 0: Cf = acc + bias + resid (fp32 out)
// MODE 1: Cb = bf16(gelu(acc + bias))
// MODE 2: qkv scatter, no bias: col -> (sel,h,d); q/k in (h,b,t,d) layout,
//         v transposed: vt[(h*2+b)*64 + d][t] (packed 8B stores)
template<int MODE, int TN>
__global__ __launch_bounds__(256) void gemm_bf16(
    const ushort* __restrict__ A, int lda,
    const ushort* __restrict__ Bt, int K,
    const float* __restrict__ bias,
    const float* __restrict__ resid, int ldr,
    float* __restrict__ Cf, ushort* __restrict__ Cb, int ldc,
    ushort* __restrict__ qo, ushort* __restrict__ ko, ushort* __restrict__ vo)
{
    constexpr int WCN = TN / 2;      // wave n-extent
    constexpr int NI  = WCN / 16;    // 16-col blocks per wave
    constexpr int BI  = TN / 64;     // B staging instrs per wave
    __shared__ ushort As[128 * 32];
    __shared__ ushort Bs[TN * 32];
    int tid = threadIdx.x, wv = tid >> 6, lid = tid & 63;
    int m0 = blockIdx.x * 128, n0 = blockIdx.y * TN;
    int wr = wv >> 1, wc = wv & 1;
    int hm = lid & 15, hk = lid >> 4;

    f32x4 acc[4][NI];
    #pragma unroll
    for (int i = 0; i < 4; ++i)
        #pragma unroll
        for (int j = 0; j < NI; ++j) acc[i][j] = (f32x4){0.f, 0.f, 0.f, 0.f};

    const ushort* Abase = A + (size_t)m0 * lda;
    const ushort* Bbase = Bt + (size_t)n0 * K;

    for (int k0 = 0; k0 < K; k0 += 32) {
        __syncthreads();
        #pragma unroll
        for (int i = 0; i < 2; ++i) {
            int c = wv * 128 + i * 64 + lid;      // LDS chunk id
            int r = c >> 2;
            int j = (c ^ (r ^ (r >> 2))) & 3;     // source chunk (swizzle inverse)
            load_lds16(Abase + (size_t)r * lda + k0 + j * 8,
                       &As[(wv * 128 + i * 64) * 8]);
        }
        #pragma unroll
        for (int i = 0; i < BI; ++i) {
            int c = wv * (BI * 64) + i * 64 + lid;
            int r = c >> 2;
            int j = (c ^ (r ^ (r >> 2))) & 3;
            load_lds16(Bbase + (size_t)r * K + k0 + j * 8,
                       &Bs[(wv * (BI * 64) + i * 64) * 8]);
        }
        __syncthreads();
        bf16x8 af[4], bfr[NI];
        #pragma unroll
        for (int mi = 0; mi < 4; ++mi)
            af[mi] = *(const bf16x8*)&As[sw_off(wr * 64 + mi * 16 + hm, hk)];
        #pragma unroll
        for (int ni = 0; ni < NI; ++ni)
            bfr[ni] = *(const bf16x8*)&Bs[sw_off(wc * WCN + ni * 16 + hm, hk)];
        #pragma unroll
        for (int mi = 0; mi < 4; ++mi)
            #pragma unroll
            for (int ni = 0; ni < NI; ++ni)
                acc[mi][ni] = __builtin_amdgcn_mfma_f32_16x16x32_bf16(
                    af[mi], bfr[ni], acc[mi][ni], 0, 0, 0);
    }

    int colbase = n0 + wc * WCN + hm;
    int rowbase = m0 + wr * 64 + hk * 4;
    if (MODE == 0) {
        #pragma unroll
        for (int ni = 0; ni < NI; ++ni) {
            int col = colbase + ni * 16;
            float bb = bias[col];
            #pragma unroll
            for (int mi = 0; mi < 4; ++mi) {
                int row = rowbase + mi * 16;
                #pragma unroll
                for (int r = 0; r < 4; ++r)
                    Cf[(size_t)(row + r) * ldc + col] =
                        acc[mi][ni][r] + bb + resid[(size_t)(row + r) * ldr + col];
            }
        }
    } else if (MODE == 1) {
        #pragma unroll
        for (int ni = 0; ni < NI; ++ni) {
            int col = colbase + ni * 16;
            float bb = bias[col];
            #pragma unroll
            for (int mi = 0; mi < 4; ++mi) {
                int row = rowbase + mi * 16;
                #pragma unroll
                for (int r = 0; r < 4; ++r)
                    Cb[(size_t)(row + r) * ldc + col] =
                        f2bfu(gelu_f(acc[mi][ni][r] + bb));
            }
        }
    } else {
        #pragma unroll
        for (int ni = 0; ni < NI; ++ni) {
            int col = colbase + ni * 16;           // 0..3071
            int sel = col >> 10, cc = col & 1023;
            int h = cc >> 6, d = cc & 63;
            if (sel < 2) {
                ushort* outp = (sel == 0 ? qo : ko)
                             + (size_t)h * (Mrows * DHn) + d;
                #pragma unroll
                for (int mi = 0; mi < 4; ++mi) {
                    int row = rowbase + mi * 16;
                    #pragma unroll
                    for (int r = 0; r < 4; ++r)
                        outp[(size_t)(row + r) * DHn] = f2bfu(acc[mi][ni][r]);
                }
            } else {
                // v transposed: vt[(h*2+b)*64 + d][t], t = row & 2047
                #pragma unroll
                for (int mi = 0; mi < 4; ++mi) {
                    int row = rowbase + mi * 16;
                    int bb2 = row >> 11, t = row & 2047;
                    ushort4 u;
                    u.x = f2bfu(acc[mi][ni][0]); u.y = f2bfu(acc[mi][ni][1]);
                    u.z = f2bfu(acc[mi][ni][2]); u.w = f2bfu(acc[mi][ni][3]);
                    *(ushort4*)(vo + ((size_t)((h * 2 + bb2) * 64 + d)) * Tn + t) = u;
                }
            }
        }
    }
}

// ---------------- MFMA flash attention v3 (unchanged from R5) ----------------
__global__ __launch_bounds__(256) void attn_mfma(
    const ushort* __restrict__ q, const ushort* __restrict__ ksrc,
    const ushort* __restrict__ vtsrc, ushort* __restrict__ cat)
{
    int g = blockIdx.x;
    int h = g >> 1, b = g & 1;
    const ushort* qg  = q     + (size_t)g * Tn * DHn;
    const ushort* kg  = ksrc  + (size_t)g * Tn * DHn;
    const ushort* vtg = vtsrc + (size_t)g * DHn * Tn;   // [d][t]
    int tid = threadIdx.x, wave = tid >> 6, lane = tid & 63;
    int m = lane & 15, gq = lane >> 4;

    __shared__ short Ks[4096];      // [key(64)][d(64)] swizzled
    __shared__ short Vt[4096];      // [d(64)][key(64)] swizzled
    __shared__ short Ps[4][1024];   // per-wave [q(16)][key(64)] swizzled

    int R  = tid >> 2;   // staging row 0..63
    int c2 = tid & 3;    // staging 16-elem chunk

    #pragma unroll 1
    for (int phase = 0; phase < 2; ++phase) {
        int qt = phase ? (31 - (int)blockIdx.y) : (int)blockIdx.y;
        int q0 = qt * 64;

        bf16x8 qf[2];
        {
            const ushort* qp = qg + (size_t)(q0 + wave * 16 + m) * DHn + gq * 8;
            qf[0] = *(const bf16x8*)(qp);
            qf[1] = *(const bf16x8*)(qp + 32);
        }
        f32x4 o[4];
        #pragma unroll
        for (int i = 0; i < 4; ++i) o[i] = (f32x4){0.f, 0.f, 0.f, 0.f};
        float lsum[4] = {0.f, 0.f, 0.f, 0.f};

        for (int kt = 0; kt <= qt; ++kt) {
            int k0 = kt * 64;
            __syncthreads();
            {   // stage K tile [key][d] and V^T tile [d][key], both b128 swizzled
                const ushort* ksp = kg  + (size_t)(k0 + R) * DHn + c2 * 16;
                const ushort* vsp = vtg + (size_t)R * Tn + k0 + c2 * 16;
                bf16x8 f0 = *(const bf16x8*)(ksp);
                bf16x8 f1 = *(const bf16x8*)(ksp + 8);
                bf16x8 v0 = *(const bf16x8*)(vsp);
                bf16x8 v1 = *(const bf16x8*)(vsp + 8);
                *(bf16x8*)&Ks[R * 64 + (((c2 * 2    ) ^ (R & 7)) << 3)] = f0;
                *(bf16x8*)&Ks[R * 64 + (((c2 * 2 + 1) ^ (R & 7)) << 3)] = f1;
                *(bf16x8*)&Vt[R * 64 + (((c2 * 2    ) ^ (R & 7)) << 3)] = v0;
                *(bf16x8*)&Vt[R * 64 + (((c2 * 2 + 1) ^ (R & 7)) << 3)] = v1;
            }
            __syncthreads();

            bool diag = (kt == qt);
            float ps[4][4];
            #pragma unroll
            for (int ct = 0; ct < 4; ++ct) {
                if (diag && ct > wave) {   // fully masked sub-tile
                    ps[ct][0] = ps[ct][1] = ps[ct][2] = ps[ct][3] = 0.f;
                    continue;
                }
                f32x4 acc = (f32x4){0.f, 0.f, 0.f, 0.f};
                int row = ct * 16 + m;     // key within tile
                #pragma unroll
                for (int db = 0; db < 2; ++db) {
                    bf16x8 kf = *(const bf16x8*)&Ks[row * 64 + (((db * 4 + gq) ^ (row & 7)) << 3)];
                    acc = __builtin_amdgcn_mfma_f32_16x16x32_bf16(qf[db], kf, acc, 0, 0, 0);
                }
                #pragma unroll
                for (int r = 0; r < 4; ++r) {
                    float p;
                    if (diag && (ct * 16 + m) > (wave * 16 + gq * 4 + r)) {
                        p = 0.f;
                    } else {
                        p = __expf(acc[r] * 0.125f);   // 1/sqrt(64)
                    }
                    ps[ct][r] = p;
                    lsum[r] += p;
                }
            }

            // P (C-layout) -> LDS -> A-layout fragments (per-wave buffer)
            #pragma unroll
            for (int ct = 0; ct < 4; ++ct)
                #pragma unroll
                for (int r = 0; r < 4; ++r) {
                    int row = gq * 4 + r;
                    Ps[wave][row * 64 + ((((ct * 2 + (m >> 3)) ^ (row & 7)) << 3) | (m & 7))] =
                        f2bf(ps[ct][r]);
                }
            bf16x8 pf[2];
            #pragma unroll
            for (int db2 = 0; db2 < 2; ++db2)
                pf[db2] = *(const bf16x8*)&Ps[wave][m * 64 + (((db2 * 4 + gq) ^ (m & 7)) << 3)];

            #pragma unroll
            for (int ct2 = 0; ct2 < 4; ++ct2) {
                int row = ct2 * 16 + m;   // d index
                #pragma unroll
                for (int db2 = 0; db2 < 2; ++db2) {
                    bf16x8 vf = *(const bf16x8*)&Vt[row * 64 + (((db2 * 4 + gq) ^ (row & 7)) << 3)];
                    o[ct2] = __builtin_amdgcn_mfma_f32_16x16x32_bf16(pf[db2], vf, o[ct2], 0, 0, 0);
                }
            }
        }

        // epilogue: reduce l across the 16-lane row group, scale, quirk write
        float inv[4];
        #pragma unroll
        for (int r = 0; r < 4; ++r) {
            float l = lsum[r];
            l += __shfl_xor(l, 1);
            l += __shfl_xor(l, 2);
            l += __shfl_xor(l, 4);
            l += __shfl_xor(l, 8);
            inv[r] = 1.0f / l;
        }
        size_t base = (size_t)b * Tn * En + (size_t)h * 64 + (size_t)qt * En
                    + wave * 16 + gq * 4;
        #pragma unroll
        for (int ct2 = 0; ct2 < 4; ++ct2) {
            int d = ct2 * 16 + m;
            #pragma unroll
            for (int r = 0; r < 4; ++r)
                cat[base + (size_t)d * 32 * En + r] = f2bfu(o[ct2][r] * inv[r]);
        }
    }
}

extern "C" void kernel_launch(void* const* d_in, const int* in_sizes, int n_in,
                              void* d_out, int out_size, void* d_ws, size_t ws_size,
                              hipStream_t stream) {
    const float* x     = (const float*)d_in[0];
    const float* Wq    = (const float*)d_in[1];
    const float* Wk    = (const float*)d_in[2];
    const float* Wv    = (const float*)d_in[3];
    const float* fc_w  = (const float*)d_in[4];
    const float* fc_b  = (const float*)d_in[5];
    const float* ln1_s = (const float*)d_in[6];
    const float* ln1_b = (const float*)d_in[7];
    const float* ln2_s = (const float*)d_in[8];
    const float* ln2_b = (const float*)d_in[9];
    const float* ff_w1 = (const float*)d_in[10];
    const float* ff_b1 = (const float*)d_in[11];
    const float* ff_w2 = (const float*)d_in[12];
    const float* ff_b2 = (const float*)d_in[13];
    float* out = (float*)d_out;
    (void)in_sizes; (void)n_in; (void)out_size; (void)ws_size;

    const size_t MB = 1048576;
    char* w8 = (char*)d_ws;
    ushort* S0   = (ushort*)(w8 + 0 * MB);    // xn_bf / cat_bf (8MB)
    ushort* kb   = (ushort*)(w8 + 8 * MB);    // k bf16 (8MB)
    ushort* vtb  = (ushort*)(w8 + 16 * MB);   // v^T bf16 [g][d][t] (8MB)
    ushort* qb   = (ushort*)(w8 + 24 * MB);   // q bf16 / ynb_bf (8MB)
    float*  hb   = (float*)(w8 + 32 * MB);    // h fp32 (16MB)
    ushort* y1   = (ushort*)(w8 + 48 * MB);   // gelu out bf16 [4096][4096] (32MB)
    ushort* wqkv = (ushort*)(w8 + 80 * MB);   // [3072][1024] (6MB)
    ushort* wfc  = (ushort*)(w8 + 86 * MB);   // [1024][1024] (2MB)
    ushort* wf1  = (ushort*)(w8 + 88 * MB);   // [4096][1024] (8MB)
    ushort* wf2  = (ushort*)(w8 + 96 * MB);   // [1024][4096] (8MB) -> 104MB total

    // weight prep
    transpose_qkv<<<dim3(16, 1, 48), 256, 0, stream>>>(Wq, Wk, Wv, wqkv);
    transpose_w<<<dim3(16, 16), 256, 0, stream>>>(fc_w, wfc, En, En);
    transpose_w<<<dim3(16, 64), 256, 0, stream>>>(ff_w1, wf1, En, 4 * En);
    transpose_w<<<dim3(64, 16), 256, 0, stream>>>(ff_w2, wf2, 4 * En, En);

    // LN1 -> xn (bf16)
    ln_kernel<<<dim3(Mrows), 256, 0, stream>>>(x, ln1_s, ln1_b, S0);
    // QKV: [4096,1024] x [3072,1024]^T, scatter epilogue (v transposed)
    gemm_bf16<2, 128><<<dim3(32, 24), 256, 0, stream>>>(
        S0, En, wqkv, En, nullptr, nullptr, 0, nullptr, nullptr, 0, qb, kb, vtb);
    // attention -> cat (bf16, quirk layout), reuses S0
    attn_mfma<<<dim3(Hn * Bn, 16), 256, 0, stream>>>(qb, kb, vtb, S0);
    // fc: h = cat @ fc_w + fc_b + x  (fp32 out), 128x64 tile -> 512 blocks
    gemm_bf16<0, 64><<<dim3(32, 16), 256, 0, stream>>>(
        S0, En, wfc, En, fc_b, x, En, hb, nullptr, En, nullptr, nullptr, nullptr);
    // LN2 -> ynb (bf16, reuses qb)
    ln_kernel<<<dim3(Mrows), 256, 0, stream>>>(hb, ln2_s, ln2_b, qb);
    // ff1: y1 = gelu(ynb @ ff_w1 + ff_b1)  (bf16 out)
    gemm_bf16<1, 128><<<dim3(32, 32), 256, 0, stream>>>(
        qb, En, wf1, En, ff_b1, nullptr, 0, nullptr, y1, 4 * En, nullptr, nullptr, nullptr);
    // ff2: out = y1 @ ff_w2 + ff_b2 + h  (fp32 out), 128x64 tile -> 512 blocks
    gemm_bf16<0, 64><<<dim3(32, 16), 256, 0, stream>>>(
        y1, 4 * En, wf2, 4 * En, ff_b2, hb, En, out, nullptr, En, nullptr, nullptr, nullptr);
}

// Round 7
// 353.670 us; speedup vs baseline: 7.8611x; 1.1466x over previous
//
#include <hip/hip_runtime.h>

// Transformer block. B=2 T=2048 E=1024 H=16 DH=64.
// R7: GEMM restructure — BK=64 (half the barrier drains), 8-chunk XOR LDS
// swizzle (2-way max on fragment reads), split-K=2 for the N=1024 GEMMs
// (fc, ff2 -> 1024 blocks = 4/CU) with fused reduce kernels (fc-reduce
// absorbs LN2; ff2-reduce absorbs bias+resid). Attention unchanged.

#define En 1024
#define Hn 16
#define DHn 64
#define Bn 2
#define Tn 2048
#define Mrows 4096  // B*T

typedef __attribute__((ext_vector_type(8))) short bf16x8;
typedef __attribute__((ext_vector_type(4))) float f32x4;

__device__ __forceinline__ short f2bf(float f) {
    unsigned u = __float_as_uint(f);
    u += 0x7FFFu + ((u >> 16) & 1u);   // round-to-nearest-even
    return (short)(u >> 16);
}
__device__ __forceinline__ ushort f2bfu(float f) {
    unsigned u = __float_as_uint(f);
    u += 0x7FFFu + ((u >> 16) & 1u);
    return (ushort)(u >> 16);
}

__device__ __forceinline__ float gelu_f(float x) {
    float inner = 0.79788456080286535588f * x + 0.044715f * x * x * x;
    return 0.5f * x * (1.0f + tanhf(inner));
}

// async global->LDS, 16B per lane; LDS dest = wave-uniform base + lane*16
__device__ __forceinline__ void load_lds16(const void* g, void* l) {
    __builtin_amdgcn_global_load_lds(
        (const __attribute__((address_space(1))) unsigned int*)(uintptr_t)g,
        (__attribute__((address_space(3))) unsigned int*)(uintptr_t)l,
        16, 0, 0);
}

// ---------------- LayerNorm: one block per row, bf16 out ----------------
__global__ __launch_bounds__(256) void ln_kernel(
    const float* __restrict__ in, const float* __restrict__ sc,
    const float* __restrict__ sh, ushort* __restrict__ out)
{
    int row = blockIdx.x;
    int tid = threadIdx.x;
    float4 v = ((const float4*)(in + (size_t)row * En))[tid];
    float s  = v.x + v.y + v.z + v.w;
    float s2 = v.x*v.x + v.y*v.y + v.z*v.z + v.w*v.w;
    #pragma unroll
    for (int off = 32; off > 0; off >>= 1) {
        s  += __shfl_down(s,  off);
        s2 += __shfl_down(s2, off);
    }
    __shared__ float red[2][4];
    int wave = tid >> 6, lane = tid & 63;
    if (lane == 0) { red[0][wave] = s; red[1][wave] = s2; }
    __syncthreads();
    s  = red[0][0] + red[0][1] + red[0][2] + red[0][3];
    s2 = red[1][0] + red[1][1] + red[1][2] + red[1][3];
    float mean = s * (1.0f / En);
    float var  = s2 * (1.0f / En) - mean * mean;
    float r = rsqrtf(var + 1e-5f);
    float4 scv = ((const float4*)sc)[tid];
    float4 shv = ((const float4*)sh)[tid];
    ushort4 o;
    o.x = f2bfu(scv.x * (v.x - mean) * r + shv.x);
    o.y = f2bfu(scv.y * (v.y - mean) * r + shv.y);
    o.z = f2bfu(scv.z * (v.z - mean) * r + shv.z);
    o.w = f2bfu(scv.w * (v.w - mean) * r + shv.w);
    ((ushort4*)(out + (size_t)row * En))[tid] = o;
}

// ---- fc split-K reduce fused with residual + LN2: one block per row ----
__global__ __launch_bounds__(256) void ln2_fuse(
    const float* __restrict__ P0, const float* __restrict__ P1,
    const float* __restrict__ bias, const float* __restrict__ x,
    const float* __restrict__ sc, const float* __restrict__ sh,
    float* __restrict__ hb, ushort* __restrict__ ynb)
{
    int row = blockIdx.x, tid = threadIdx.x;
    size_t idx = (size_t)row * 256 + tid;
    float4 a  = ((const float4*)P0)[idx];
    float4 b  = ((const float4*)P1)[idx];
    float4 bi = ((const float4*)bias)[tid];
    float4 xr = ((const float4*)x)[idx];
    float4 v;
    v.x = a.x + b.x + bi.x + xr.x;
    v.y = a.y + b.y + bi.y + xr.y;
    v.z = a.z + b.z + bi.z + xr.z;
    v.w = a.w + b.w + bi.w + xr.w;
    ((float4*)hb)[idx] = v;
    float s  = v.x + v.y + v.z + v.w;
    float s2 = v.x*v.x + v.y*v.y + v.z*v.z + v.w*v.w;
    #pragma unroll
    for (int off = 32; off > 0; off >>= 1) {
        s  += __shfl_down(s,  off);
        s2 += __shfl_down(s2, off);
    }
    __shared__ float red[2][4];
    int wave = tid >> 6, lane = tid & 63;
    if (lane == 0) { red[0][wave] = s; red[1][wave] = s2; }
    __syncthreads();
    s  = red[0][0] + red[0][1] + red[0][2] + red[0][3];
    s2 = red[1][0] + red[1][1] + red[1][2] + red[1][3];
    float mean = s * (1.0f / En);
    float var  = s2 * (1.0f / En) - mean * mean;
    float r = rsqrtf(var + 1e-5f);
    float4 scv = ((const float4*)sc)[tid];
    float4 shv = ((const float4*)sh)[tid];
    ushort4 o;
    o.x = f2bfu(scv.x * (v.x - mean) * r + shv.x);
    o.y = f2bfu(scv.y * (v.y - mean) * r + shv.y);
    o.z = f2bfu(scv.z * (v.z - mean) * r + shv.z);
    o.w = f2bfu(scv.w * (v.w - mean) * r + shv.w);
    ((ushort4*)ynb)[idx] = o;
}

// ---- ff2 split-K reduce fused with bias + residual -> out ----
__global__ __launch_bounds__(256) void ff2_reduce(
    const float* __restrict__ P0, const float* __restrict__ P1,
    const float* __restrict__ bias, const float* __restrict__ hb,
    float* __restrict__ out)
{
    int tid = threadIdx.x;
    size_t i = (size_t)blockIdx.x * 256 + tid;
    float4 a  = ((const float4*)P0)[i];
    float4 b  = ((const float4*)P1)[i];
    float4 bi = ((const float4*)bias)[tid];   // 1024 cols = 256 float4, col4 == tid
    float4 h  = ((const float4*)hb)[i];
    float4 o;
    o.x = a.x + b.x + bi.x + h.x;
    o.y = a.y + b.y + bi.y + h.y;
    o.z = a.z + b.z + bi.z + h.z;
    o.w = a.w + b.w + bi.w + h.w;
    ((float4*)out)[i] = o;
}

// ---------------- weight transpose+convert: out[n*K+k] = bf16(in[k*N+n]) ----
__global__ __launch_bounds__(256) void transpose_w(
    const float* __restrict__ in, ushort* __restrict__ out, int K, int N)
{
    __shared__ float t[64][65];
    int k0 = blockIdx.x * 64, n0 = blockIdx.y * 64;
    int tid = threadIdx.x, r = tid >> 4, c4 = (tid & 15) * 4;
    #pragma unroll
    for (int i = 0; i < 4; ++i) {
        float4 v = *(const float4*)(in + (size_t)(k0 + r + i * 16) * N + n0 + c4);
        t[r + i * 16][c4 + 0] = v.x; t[r + i * 16][c4 + 1] = v.y;
        t[r + i * 16][c4 + 2] = v.z; t[r + i * 16][c4 + 3] = v.w;
    }
    __syncthreads();
    #pragma unroll
    for (int i = 0; i < 4; ++i) {
        int n = r + i * 16;
        ushort4 u;
        u.x = f2bfu(t[c4 + 0][n]); u.y = f2bfu(t[c4 + 1][n]);
        u.z = f2bfu(t[c4 + 2][n]); u.w = f2bfu(t[c4 + 3][n]);
        *(ushort4*)(out + (size_t)(n0 + n) * K + k0 + c4) = u;
    }
}

// qkv weights: Wq/Wk/Wv [H][E][DH] -> combined B^T [3072][1024]
__global__ __launch_bounds__(256) void transpose_qkv(
    const float* __restrict__ Wq, const float* __restrict__ Wk,
    const float* __restrict__ Wv, ushort* __restrict__ out)
{
    __shared__ float t[64][65];
    int z = blockIdx.z, sel = z >> 4, h = z & 15;
    const float* in = (sel == 0 ? Wq : sel == 1 ? Wk : Wv) + (size_t)h * En * DHn;
    ushort* o = out + ((size_t)(sel * 1024 + h * 64)) * En;
    int k0 = blockIdx.x * 64;
    int tid = threadIdx.x, r = tid >> 4, c4 = (tid & 15) * 4;
    #pragma unroll
    for (int i = 0; i < 4; ++i) {
        float4 v = *(const float4*)(in + (size_t)(k0 + r + i * 16) * DHn + c4);
        t[r + i * 16][c4 + 0] = v.x; t[r + i * 16][c4 + 1] = v.y;
        t[r + i * 16][c4 + 2] = v.z; t[r + i * 16][c4 + 3] = v.w;
    }
    __syncthreads();
    #pragma unroll
    for (int i = 0; i < 4; ++i) {
        int n = r + i * 16;   // d index 0..63
        ushort4 u;
        u.x = f2bfu(t[c4 + 0][n]); u.y = f2bfu(t[c4 + 1][n]);
        u.z = f2bfu(t[c4 + 2][n]); u.w = f2bfu(t[c4 + 3][n]);
        *(ushort4*)(o + (size_t)n * En + k0 + c4) = u;
    }
}

// ---------------- bf16 MFMA GEMM: C[M][N] = A[M][K] * Bt[N][K]^T -----------
// 128 x TN tile, BK=64 (rows of 8 16B-chunks, slot = j ^ (r&7) swizzle).
// MODE 1: Cb = bf16(gelu(acc + bias))
// MODE 2: qkv scatter: col -> (sel,h,d); q/k (h,b,t,d), v^T [g*64+d][t]
// MODE 3: split-K partial: Cf + z*M*ldc <- raw acc (fp32)
template<int MODE, int TN>
__global__ __launch_bounds__(256) void gemm_bf16(
    const ushort* __restrict__ A, int lda,
    const ushort* __restrict__ Bt, int ldb, int Kloop,
    const float* __restrict__ bias,
    float* __restrict__ Cf, ushort* __restrict__ Cb, int ldc,
    ushort* __restrict__ qo, ushort* __restrict__ ko, ushort* __restrict__ vo)
{
    constexpr int WCN = TN / 2;        // wave n-extent
    constexpr int NI  = WCN / 16;      // 16-col blocks per wave
    constexpr int BIW = TN * 8 / 256;  // B staging instrs per wave (TN=128:4, 64:2)
    __shared__ ushort As[128 * 64];
    __shared__ ushort Bs[TN * 64];
    int tid = threadIdx.x, wv = tid >> 6, lid = tid & 63;
    int m0 = blockIdx.x * 128, n0 = blockIdx.y * TN;
    int koff = blockIdx.z * Kloop;
    int wr = wv >> 1, wc = wv & 1;
    int hm = lid & 15, hk = lid >> 4;

    f32x4 acc[4][NI];
    #pragma unroll
    for (int i = 0; i < 4; ++i)
        #pragma unroll
        for (int j = 0; j < NI; ++j) acc[i][j] = (f32x4){0.f, 0.f, 0.f, 0.f};

    const ushort* Abase = A + (size_t)m0 * lda + koff;
    const ushort* Bbase = Bt + (size_t)n0 * ldb + koff;

    for (int k0 = 0; k0 < Kloop; k0 += 64) {
        __syncthreads();
        #pragma unroll
        for (int i = 0; i < 4; ++i) {       // A: 1024 chunks, 4/lane
            int c = wv * 256 + i * 64 + lid;
            int r = c >> 3, s = c & 7;
            int j = s ^ (r & 7);            // source k-chunk for this LDS slot
            load_lds16(Abase + (size_t)r * lda + k0 + j * 8,
                       &As[(wv * 256 + i * 64) * 8]);
        }
        #pragma unroll
        for (int i = 0; i < BIW; ++i) {
            int c = wv * (BIW * 64) + i * 64 + lid;
            int r = c >> 3, s = c & 7;
            int j = s ^ (r & 7);
            load_lds16(Bbase + (size_t)r * ldb + k0 + j * 8,
                       &Bs[(wv * (BIW * 64) + i * 64) * 8]);
        }
        __syncthreads();
        #pragma unroll
        for (int kk = 0; kk < 2; ++kk) {
            bf16x8 af[4], bfr[NI];
            #pragma unroll
            for (int mi = 0; mi < 4; ++mi) {
                int r = wr * 64 + mi * 16 + hm;
                int slot = ((kk << 2) | hk) ^ (r & 7);
                af[mi] = *(const bf16x8*)&As[(r * 8 + slot) * 8];
            }
            #pragma unroll
            for (int ni = 0; ni < NI; ++ni) {
                int r = wc * WCN + ni * 16 + hm;
                int slot = ((kk << 2) | hk) ^ (r & 7);
                bfr[ni] = *(const bf16x8*)&Bs[(r * 8 + slot) * 8];
            }
            #pragma unroll
            for (int mi = 0; mi < 4; ++mi)
                #pragma unroll
                for (int ni = 0; ni < NI; ++ni)
                    acc[mi][ni] = __builtin_amdgcn_mfma_f32_16x16x32_bf16(
                        af[mi], bfr[ni], acc[mi][ni], 0, 0, 0);
        }
    }

    int colbase = n0 + wc * WCN + hm;
    int rowbase = m0 + wr * 64 + hk * 4;
    if (MODE == 1) {
        #pragma unroll
        for (int ni = 0; ni < NI; ++ni) {
            int col = colbase + ni * 16;
            float bb = bias[col];
            #pragma unroll
            for (int mi = 0; mi < 4; ++mi) {
                int row = rowbase + mi * 16;
                #pragma unroll
                for (int r = 0; r < 4; ++r)
                    Cb[(size_t)(row + r) * ldc + col] =
                        f2bfu(gelu_f(acc[mi][ni][r] + bb));
            }
        }
    } else if (MODE == 2) {
        #pragma unroll
        for (int ni = 0; ni < NI; ++ni) {
            int col = colbase + ni * 16;           // 0..3071
            int sel = col >> 10, cc = col & 1023;
            int h = cc >> 6, d = cc & 63;
            if (sel < 2) {
                ushort* outp = (sel == 0 ? qo : ko)
                             + (size_t)h * (Mrows * DHn) + d;
                #pragma unroll
                for (int mi = 0; mi < 4; ++mi) {
                    int row = rowbase + mi * 16;
                    #pragma unroll
                    for (int r = 0; r < 4; ++r)
                        outp[(size_t)(row + r) * DHn] = f2bfu(acc[mi][ni][r]);
                }
            } else {
                // v transposed: vt[(h*2+b)*64 + d][t], t = row & 2047
                #pragma unroll
                for (int mi = 0; mi < 4; ++mi) {
                    int row = rowbase + mi * 16;
                    int bb2 = row >> 11, t = row & 2047;
                    ushort4 u;
                    u.x = f2bfu(acc[mi][ni][0]); u.y = f2bfu(acc[mi][ni][1]);
                    u.z = f2bfu(acc[mi][ni][2]); u.w = f2bfu(acc[mi][ni][3]);
                    *(ushort4*)(vo + ((size_t)((h * 2 + bb2) * 64 + d)) * Tn + t) = u;
                }
            }
        }
    } else {
        float* Cp = Cf + (size_t)blockIdx.z * Mrows * ldc;
        #pragma unroll
        for (int ni = 0; ni < NI; ++ni) {
            int col = colbase + ni * 16;
            #pragma unroll
            for (int mi = 0; mi < 4; ++mi) {
                int row = rowbase + mi * 16;
                #pragma unroll
                for (int r = 0; r < 4; ++r)
                    Cp[(size_t)(row + r) * ldc + col] = acc[mi][ni][r];
            }
        }
    }
}

// ---------------- MFMA flash attention v3 (unchanged from R5) ----------------
__global__ __launch_bounds__(256) void attn_mfma(
    const ushort* __restrict__ q, const ushort* __restrict__ ksrc,
    const ushort* __restrict__ vtsrc, ushort* __restrict__ cat)
{
    int g = blockIdx.x;
    int h = g >> 1, b = g & 1;
    const ushort* qg  = q     + (size_t)g * Tn * DHn;
    const ushort* kg  = ksrc  + (size_t)g * Tn * DHn;
    const ushort* vtg = vtsrc + (size_t)g * DHn * Tn;   // [d][t]
    int tid = threadIdx.x, wave = tid >> 6, lane = tid & 63;
    int m = lane & 15, gq = lane >> 4;

    __shared__ short Ks[4096];      // [key(64)][d(64)] swizzled
    __shared__ short Vt[4096];      // [d(64)][key(64)] swizzled
    __shared__ short Ps[4][1024];   // per-wave [q(16)][key(64)] swizzled

    int R  = tid >> 2;   // staging row 0..63
    int c2 = tid & 3;    // staging 16-elem chunk

    #pragma unroll 1
    for (int phase = 0; phase < 2; ++phase) {
        int qt = phase ? (31 - (int)blockIdx.y) : (int)blockIdx.y;
        int q0 = qt * 64;

        bf16x8 qf[2];
        {
            const ushort* qp = qg + (size_t)(q0 + wave * 16 + m) * DHn + gq * 8;
            qf[0] = *(const bf16x8*)(qp);
            qf[1] = *(const bf16x8*)(qp + 32);
        }
        f32x4 o[4];
        #pragma unroll
        for (int i = 0; i < 4; ++i) o[i] = (f32x4){0.f, 0.f, 0.f, 0.f};
        float lsum[4] = {0.f, 0.f, 0.f, 0.f};

        for (int kt = 0; kt <= qt; ++kt) {
            int k0 = kt * 64;
            __syncthreads();
            {   // stage K tile [key][d] and V^T tile [d][key], both b128 swizzled
                const ushort* ksp = kg  + (size_t)(k0 + R) * DHn + c2 * 16;
                const ushort* vsp = vtg + (size_t)R * Tn + k0 + c2 * 16;
                bf16x8 f0 = *(const bf16x8*)(ksp);
                bf16x8 f1 = *(const bf16x8*)(ksp + 8);
                bf16x8 v0 = *(const bf16x8*)(vsp);
                bf16x8 v1 = *(const bf16x8*)(vsp + 8);
                *(bf16x8*)&Ks[R * 64 + (((c2 * 2    ) ^ (R & 7)) << 3)] = f0;
                *(bf16x8*)&Ks[R * 64 + (((c2 * 2 + 1) ^ (R & 7)) << 3)] = f1;
                *(bf16x8*)&Vt[R * 64 + (((c2 * 2    ) ^ (R & 7)) << 3)] = v0;
                *(bf16x8*)&Vt[R * 64 + (((c2 * 2 + 1) ^ (R & 7)) << 3)] = v1;
            }
            __syncthreads();

            bool diag = (kt == qt);
            float ps[4][4];
            #pragma unroll
            for (int ct = 0; ct < 4; ++ct) {
                if (diag && ct > wave) {   // fully masked sub-tile
                    ps[ct][0] = ps[ct][1] = ps[ct][2] = ps[ct][3] = 0.f;
                    continue;
                }
                f32x4 acc = (f32x4){0.f, 0.f, 0.f, 0.f};
                int row = ct * 16 + m;     // key within tile
                #pragma unroll
                for (int db = 0; db < 2; ++db) {
                    bf16x8 kf = *(const bf16x8*)&Ks[row * 64 + (((db * 4 + gq) ^ (row & 7)) << 3)];
                    acc = __builtin_amdgcn_mfma_f32_16x16x32_bf16(qf[db], kf, acc, 0, 0, 0);
                }
                #pragma unroll
                for (int r = 0; r < 4; ++r) {
                    float p;
                    if (diag && (ct * 16 + m) > (wave * 16 + gq * 4 + r)) {
                        p = 0.f;
                    } else {
                        p = __expf(acc[r] * 0.125f);   // 1/sqrt(64)
                    }
                    ps[ct][r] = p;
                    lsum[r] += p;
                }
            }

            // P (C-layout) -> LDS -> A-layout fragments (per-wave buffer)
            #pragma unroll
            for (int ct = 0; ct < 4; ++ct)
                #pragma unroll
                for (int r = 0; r < 4; ++r) {
                    int row = gq * 4 + r;
                    Ps[wave][row * 64 + ((((ct * 2 + (m >> 3)) ^ (row & 7)) << 3) | (m & 7))] =
                        f2bf(ps[ct][r]);
                }
            bf16x8 pf[2];
            #pragma unroll
            for (int db2 = 0; db2 < 2; ++db2)
                pf[db2] = *(const bf16x8*)&Ps[wave][m * 64 + (((db2 * 4 + gq) ^ (m & 7)) << 3)];

            #pragma unroll
            for (int ct2 = 0; ct2 < 4; ++ct2) {
                int row = ct2 * 16 + m;   // d index
                #pragma unroll
                for (int db2 = 0; db2 < 2; ++db2) {
                    bf16x8 vf = *(const bf16x8*)&Vt[row * 64 + (((db2 * 4 + gq) ^ (row & 7)) << 3)];
                    o[ct2] = __builtin_amdgcn_mfma_f32_16x16x32_bf16(pf[db2], vf, o[ct2], 0, 0, 0);
                }
            }
        }

        // epilogue: reduce l across the 16-lane row group, scale, quirk write
        float inv[4];
        #pragma unroll
        for (int r = 0; r < 4; ++r) {
            float l = lsum[r];
            l += __shfl_xor(l, 1);
            l += __shfl_xor(l, 2);
            l += __shfl_xor(l, 4);
            l += __shfl_xor(l, 8);
            inv[r] = 1.0f / l;
        }
        size_t base = (size_t)b * Tn * En + (size_t)h * 64 + (size_t)qt * En
                    + wave * 16 + gq * 4;
        #pragma unroll
        for (int ct2 = 0; ct2 < 4; ++ct2) {
            int d = ct2 * 16 + m;
            #pragma unroll
            for (int r = 0; r < 4; ++r)
                cat[base + (size_t)d * 32 * En + r] = f2bfu(o[ct2][r] * inv[r]);
        }
    }
}

extern "C" void kernel_launch(void* const* d_in, const int* in_sizes, int n_in,
                              void* d_out, int out_size, void* d_ws, size_t ws_size,
                              hipStream_t stream) {
    const float* x     = (const float*)d_in[0];
    const float* Wq    = (const float*)d_in[1];
    const float* Wk    = (const float*)d_in[2];
    const float* Wv    = (const float*)d_in[3];
    const float* fc_w  = (const float*)d_in[4];
    const float* fc_b  = (const float*)d_in[5];
    const float* ln1_s = (const float*)d_in[6];
    const float* ln1_b = (const float*)d_in[7];
    const float* ln2_s = (const float*)d_in[8];
    const float* ln2_b = (const float*)d_in[9];
    const float* ff_w1 = (const float*)d_in[10];
    const float* ff_b1 = (const float*)d_in[11];
    const float* ff_w2 = (const float*)d_in[12];
    const float* ff_b2 = (const float*)d_in[13];
    float* out = (float*)d_out;
    (void)in_sizes; (void)n_in; (void)out_size; (void)ws_size;

    const size_t MB = 1048576;
    char* w8 = (char*)d_ws;
    ushort* S0   = (ushort*)(w8 + 0 * MB);    // xn_bf / cat_bf (8MB)
    ushort* kb   = (ushort*)(w8 + 8 * MB);    // k bf16 (8MB)
    ushort* vtb  = (ushort*)(w8 + 16 * MB);   // v^T bf16 [g][d][t] (8MB)
    ushort* qb   = (ushort*)(w8 + 24 * MB);   // q bf16 / ynb_bf (8MB)
    float*  hb   = (float*)(w8 + 32 * MB);    // h fp32 (16MB)
    ushort* y1   = (ushort*)(w8 + 48 * MB);   // gelu out bf16 (32MB)
    float*  Pfc  = (float*)(w8 + 48 * MB);    // fc partials 2x16MB (dead before ff1)
    float*  Pff2 = (float*)(w8 + 0 * MB);     // ff2 partials 2x16MB (S0..qb dead)
    ushort* wqkv = (ushort*)(w8 + 80 * MB);   // [3072][1024] (6MB)
    ushort* wfc  = (ushort*)(w8 + 86 * MB);   // [1024][1024] (2MB)
    ushort* wf1  = (ushort*)(w8 + 88 * MB);   // [4096][1024] (8MB)
    ushort* wf2  = (ushort*)(w8 + 96 * MB);   // [1024][4096] (8MB) -> 104MB total

    // weight prep
    transpose_qkv<<<dim3(16, 1, 48), 256, 0, stream>>>(Wq, Wk, Wv, wqkv);
    transpose_w<<<dim3(16, 16), 256, 0, stream>>>(fc_w, wfc, En, En);
    transpose_w<<<dim3(16, 64), 256, 0, stream>>>(ff_w1, wf1, En, 4 * En);
    transpose_w<<<dim3(64, 16), 256, 0, stream>>>(ff_w2, wf2, 4 * En, En);

    // LN1 -> xn (bf16)
    ln_kernel<<<dim3(Mrows), 256, 0, stream>>>(x, ln1_s, ln1_b, S0);
    // QKV: [4096,1024] x [3072,1024]^T, scatter epilogue (v transposed)
    gemm_bf16<2, 128><<<dim3(32, 24), 256, 0, stream>>>(
        S0, En, wqkv, En, En, nullptr, nullptr, nullptr, 0, qb, kb, vtb);
    // attention -> cat (bf16, quirk layout), reuses S0
    attn_mfma<<<dim3(Hn * Bn, 16), 256, 0, stream>>>(qb, kb, vtb, S0);
    // fc split-K=2: partials = cat @ fc_w  (fp32, 2 x 16MB at Pfc)
    gemm_bf16<3, 64><<<dim3(32, 16, 2), 256, 0, stream>>>(
        S0, En, wfc, En, En / 2, nullptr, Pfc, nullptr, En, nullptr, nullptr, nullptr);
    // reduce + bias + resid(x) -> hb, fused LN2 -> ynb (qb)
    ln2_fuse<<<dim3(Mrows), 256, 0, stream>>>(
        Pfc, Pfc + (size_t)Mrows * En, fc_b, x, ln2_s, ln2_b, hb, qb);
    // ff1: y1 = gelu(ynb @ ff_w1 + ff_b1)  (bf16 out)
    gemm_bf16<1, 128><<<dim3(32, 32), 256, 0, stream>>>(
        qb, En, wf1, En, En, ff_b1, nullptr, y1, 4 * En, nullptr, nullptr, nullptr);
    // ff2 split-K=2: partials = y1 @ ff_w2  (fp32, 2 x 16MB at Pff2)
    gemm_bf16<3, 64><<<dim3(32, 16, 2), 256, 0, stream>>>(
        y1, 4 * En, wf2, 4 * En, 2 * En, nullptr, Pff2, nullptr, En, nullptr, nullptr, nullptr);
    // reduce + bias + resid(h) -> out
    ff2_reduce<<<dim3(Mrows), 256, 0, stream>>>(
        Pff2, Pff2 + (size_t)Mrows * En, ff_b2, hb, out);
}